// Round 16
// baseline (247.884 us; speedup 1.0000x reference)
//
#include <hip/hip_runtime.h>
#include <hip/hip_bf16.h>
#include <hip/hip_fp16.h>

// Problem constants
#define B_    2
#define G_    16
#define N_    4096
#define S_    1024
#define D1_   128
#define D2_   256
#define CIN_  384
#define BG_   32
#define GN_   65536
#define GS_   16384

typedef unsigned int u32;
typedef unsigned short u16;
typedef _Float16 f16x8 __attribute__((ext_vector_type(8)));
typedef float f32x4 __attribute__((ext_vector_type(4)));

__device__ __forceinline__ u32 h2bits(__half2 h) { union { __half2 h; u32 u; } c; c.h = h; return c.u; }
__device__ __forceinline__ __half2 bits2h(u32 u) { union { __half2 h; u32 u; } c; c.u = u; return c.h; }
__device__ __forceinline__ u32 pkmax0(u32 v) {
  u32 r; asm("v_pk_max_f16 %0, %1, %2" : "=v"(r) : "v"(v), "v"(0)); return r;
}

// ---------------- workspace layout (bytes) ----------------
#define OFF_W1PK   0u           // 256*384*2 fragment-packed
#define OFF_W2PK   196608u      // 256*256*2 fragment-packed
#define OFF_XYZ2P  327680u      // 32*256*4*16
#define OFF_SUM1   851968u      // 4 x 16KB contiguous (sum1,sq1,sum2,sq2)
#define OFF_SQ1    868352u
#define OFF_SUM2   884736u
#define OFF_SQ2    901120u
#define OFF_SCPK1  917504u      // 16*128*4 packed half2 scale (BN1)
#define OFF_SHPK1  925696u      // packed half2 shift (BN1)
#define OFF_SS2    950272u      // float2 (BN2)
#define OFF_P2T    5177344u     // 32*1024*256*2 f16
#define OFF_Y2     21954560u    // f16 pre-BN2, OUT layout [b][m][gn]
#define OFF_Y1     122617856u   // f16 pre-BN1, [bg*4096+n][256]

// ---------------- prep: pack weights into MFMA-fragment order, zero stats, pack xyz2 ----------------
__launch_bounds__(256)
__global__ void prep_kernel(const float* __restrict__ W1, const float* __restrict__ W2,
                            const float* __restrict__ xyz2,
                            u16* __restrict__ W1pk, u16* __restrict__ W2pk,
                            float4* __restrict__ xyz2p, float* __restrict__ zeros)
{
  int idx = blockIdx.x * 256 + threadIdx.x;
  if (idx < 12288) {          // W1 fragments
    int lane = idx & 63, ks = (idx >> 6) % 12, mr = idx / (64 * 12);
    int m = mr * 16 + (lane & 15), k = ks * 32 + (lane >> 4) * 8;
    const float* src = W1 + (size_t)m * 384 + k;
    u16* dst = W1pk + (size_t)idx * 8;
    #pragma unroll
    for (int e = 0; e < 8; e++) dst[e] = __half_as_ushort(__float2half_rn(src[e]));
    return;
  }
  idx -= 12288;
  if (idx < 8192) {           // W2 fragments
    int lane = idx & 63, ks = (idx >> 6) % 8, mr = idx / (64 * 8);
    int m = mr * 16 + (lane & 15), k = ks * 32 + (lane >> 4) * 8;
    const float* src = W2 + (size_t)m * 256 + k;
    u16* dst = W2pk + (size_t)idx * 8;
    #pragma unroll
    for (int e = 0; e < 8; e++) dst[e] = __half_as_ushort(__float2half_rn(src[e]));
    return;
  }
  idx -= 8192;
  if (idx < 16384) { zeros[idx] = 0.f; return; }
  idx -= 16384;
  int bg = idx >> 8, q = idx & 255;
  int b = bg >> 4, g = bg & 15;
  const float* base = xyz2 + (size_t)b * 3 * GS_ + (size_t)g * S_ + q * 4;
  float4 X = *(const float4*)(base);
  float4 Y = *(const float4*)(base + GS_);
  float4 Z = *(const float4*)(base + 2 * GS_);
  float4 M;
  M.x = X.x*X.x + Y.x*Y.x + Z.x*Z.x;
  M.y = X.y*X.y + Y.y*Y.y + Z.y*Z.y;
  M.z = X.z*X.z + Y.z*Y.z + Z.z*Z.z;
  M.w = X.w*X.w + Y.w*Y.w + Z.w*Z.w;
  float4* dst = xyz2p + (size_t)idx * 4;
  dst[0] = X; dst[1] = Y; dst[2] = Z; dst[3] = M;
}

// ---------------- transpose points2 -> p2T [s][256] f16 ----------------
__launch_bounds__(256)
__global__ void t2_kernel(const float* __restrict__ p2, u16* __restrict__ p2T)
{
  __shared__ float tl[64][65];
  int bx = blockIdx.x;
  int bg = bx >> 6, r = bx & 63;
  int ct = r >> 4, st = r & 15;
  int c0 = ct * 64, s0 = st * 64;
  int b = bg >> 4, g = bg & 15;
  int t = threadIdx.x, lane = t & 63, w = t >> 6;
  const float* src = p2 + (size_t)b * D2_ * GS_ + (size_t)g * S_ + s0 + lane;
  #pragma unroll
  for (int i = 0; i < 16; i++) {
    int row = w * 16 + i;
    tl[row][lane] = src[(size_t)(c0 + row) * GS_];
  }
  __syncthreads();
  int cp = t & 31, sr = t >> 5;
  #pragma unroll
  for (int i = 0; i < 8; i++) {
    int sl = sr * 8 + i;
    u32 v = h2bits(__floats2half2_rn(tl[2 * cp][sl], tl[2 * cp + 1][sl]));
    *(u32*)(p2T + (((size_t)bg * 1024 + s0 + sl) * 256 + c0 + 2 * cp)) = v;
  }
}

// ================= GEMM1 (fused kNN, wave-uniform): 512 thr, M=256 x N=64, K=384 =========
// Phase 0: kNN for this block's 64 queries. lane(t&63)=query, wave(t>>6)=source-eighth
// -> xp reads WAVE-UNIFORM. Distance top-3 via min/med3 (value-identical to cascade);
// index tracking via the identical pre-update compares (bit-identical selection).
// p1 HBM loads issued BEFORE the kNN phase (latency hides under kNN VALU).
// Then R11 structure: B 64x768B XOR((r&15)<<4) (49152), barrier-free K-loop, out-tile reuses B.
__launch_bounds__(512, 6)
__global__ void gemm1_kernel(const u16* __restrict__ W1pk, const float* __restrict__ points1,
                             const u16* __restrict__ p2T, const float* __restrict__ xyz1,
                             const float4* __restrict__ xyz2p,
                             const float* __restrict__ bias,
                             float* __restrict__ sumw, float* __restrict__ sqw,
                             u16* __restrict__ Y1)
{
  __shared__ __align__(16) char smem[49152];
  int bx = blockIdx.x;
  int bg = bx >> 6, nt = bx & 63;
  int b = bg >> 4, g = bg & 15;
  int n0 = nt * 64;
  int t = threadIdx.x, wid = t >> 6, l = t & 63;
  int llo = l & 15, lhi = l >> 4;

  // ---- T14: issue p1 HBM loads first; latency hides under the kNN VALU phase ----
  int prow = t & 63, chgrp = t >> 6;
  const float* p1c = points1 + ((size_t)b * 128 + chgrp * 16) * (size_t)GN_
                   + (size_t)g * N_ + n0 + prow;
  float p1v[16];
  #pragma unroll
  for (int cp = 0; cp < 16; cp++) p1v[cp] = p1c[(size_t)cp * GN_];

  // ---- fused kNN: query = l, source-eighth = wid (wave-uniform xp addressing) ----
  {
    const float* x1b = xyz1 + (size_t)b * 3 * GN_ + (size_t)g * N_ + n0 + l;
    float x = x1b[0], y = x1b[GN_], z = x1b[2 * GN_];
    const float4* xp = xyz2p + (size_t)bg * 1024;
    float d0 = 3.4e38f, d1 = 3.4e38f, d2 = 3.4e38f;
    int i0 = 0, i1 = 0, i2 = 0;
    #pragma unroll 4
    for (int k = 0; k < 32; k++) {
      int q = wid * 32 + k;              // wave-uniform quad index
      float4 X = xp[q * 4 + 0], Y = xp[q * 4 + 1], Z = xp[q * 4 + 2], M = xp[q * 4 + 3];
      const float* Xa = (const float*)&X;
      const float* Ya = (const float*)&Y;
      const float* Za = (const float*)&Z;
      const float* Ma = (const float*)&M;
      #pragma unroll
      for (int u = 0; u < 4; u++) {
        float cr = x * Xa[u];
        cr = fmaf(y, Ya[u], cr);
        cr = fmaf(z, Za[u], cr);
        float d = fmaf(-2.f, cr, Ma[u]); // biased by -|x1|^2; consistent within a query
        int s = q * 4 + u;
        bool cc2 = d < d2, cc1 = d < d1, cc0 = d < d0;
        i2 = cc1 ? i1 : (cc2 ? s : i2);
        i1 = cc0 ? i0 : (cc1 ? s : i1);
        i0 = cc0 ? s : i0;
        d2 = __builtin_amdgcn_fmed3f(d1, d2, d);   // == cc1?d1:(cc2?d:d2)
        d1 = __builtin_amdgcn_fmed3f(d0, d1, d);   // == cc0?d0:(cc1?d:d1)
        d0 = fminf(d0, d);
      }
    }
    float* sd = (float*)smem;            // [3][512] = 6144 B
    int*   si = (int*)(smem + 6144);     // [3][512] = 6144 B
    sd[0 * 512 + t] = d0; sd[1 * 512 + t] = d1; sd[2 * 512 + t] = d2;
    si[0 * 512 + t] = i0; si[1 * 512 + t] = i1; si[2 * 512 + t] = i2;
    __syncthreads();
    if (t < 64) {                        // wid==0 thread merges eighths 1..7 for query t
      float D0 = d0, D1 = d1, D2 = d2;
      int I0 = i0, I1 = i1, I2 = i2;
      #pragma unroll
      for (int e = 1; e < 8; e++) {
        int idx = e * 64 + t;
        #pragma unroll
        for (int c = 0; c < 3; c++) {
          float d = sd[c * 512 + idx];
          int s = si[c * 512 + idx];
          bool cc0 = d < D0, cc1 = d < D1, cc2 = d < D2;
          I2 = cc1 ? I1 : (cc2 ? s : I2);
          I1 = cc0 ? I0 : (cc1 ? s : I1);
          I0 = cc0 ? s : I0;
          D2 = __builtin_amdgcn_fmed3f(D1, D2, d);
          D1 = __builtin_amdgcn_fmed3f(D0, D1, d);
          D0 = fminf(D0, d);
        }
      }
      float m1 = x * x + y * y + z * z;
      float t0 = fmaxf(D0 + m1, 0.f), t1 = fmaxf(D1 + m1, 0.f), t2v = fmaxf(D2 + m1, 0.f);
      float w0 = 1.f / (t0 + 1e-8f);
      float w1 = 1.f / (t1 + 1e-8f);
      float w2 = 1.f / (t2v + 1e-8f);
      float inv = 1.f / (w0 + w1 + w2);
      uint4 rec;
      rec.x = h2bits(__floats2half2_rn(w0 * inv, w1 * inv));
      rec.y = (u32)__half_as_ushort(__float2half_rn(w2 * inv));
      rec.z = (u32)I0 | ((u32)I1 << 16);
      rec.w = (u32)I2;
      *(uint4*)(smem + 12288 + t * 16) = rec;
    }
    __syncthreads();
  }
  uint4 kp = *(const uint4*)(smem + 12288 + (t >> 3) * 16);  // rec for B-build row t>>3
  __syncthreads();   // all kp in regs; smem free for B-tile

  int qr = t >> 3, c8 = t & 7;            // B-build row, channel-eighth

  // ---- B-build: interp ch 128..383, 1 row per 8 threads, 4 chunks each ----
  {
    const u16* p2b = p2T + (size_t)bg * 1024 * 256;
    __half2 w0 = __half2half2(__low2half(bits2h(kp.x)));
    __half2 w1 = __half2half2(__high2half(bits2h(kp.x)));
    __half2 w2 = __half2half2(__low2half(bits2h(kp.y)));
    int i0 = kp.z & 0xffff, i1 = kp.z >> 16, i2 = kp.w & 0xffff;
    const u16* r0 = p2b + (size_t)i0 * 256;
    const u16* r1 = p2b + (size_t)i1 * 256;
    const u16* r2 = p2b + (size_t)i2 * 256;
    #pragma unroll
    for (int u = 0; u < 4; u++) {
      int ch = c8 + 8 * u;
      uint4 q0 = *(const uint4*)(r0 + ch * 8);
      uint4 q1 = *(const uint4*)(r1 + ch * 8);
      uint4 q2 = *(const uint4*)(r2 + ch * 8);
      const u32* a0 = (const u32*)&q0;
      const u32* a1 = (const u32*)&q1;
      const u32* a2 = (const u32*)&q2;
      uint4 o;
      u32* ow = (u32*)&o;
      #pragma unroll
      for (int w = 0; w < 4; w++) {
        __half2 v = __hmul2(w2, bits2h(a2[w]));
        v = __hfma2(w1, bits2h(a1[w]), v);
        v = __hfma2(w0, bits2h(a0[w]), v);
        ow[w] = h2bits(v);
      }
      *(uint4*)(smem + qr * 768 + ((256 + ch * 16) ^ ((qr & 15) << 4))) = o;
    }
    // p1 ch 0..127: write from the pre-loaded regs
    #pragma unroll
    for (int cp = 0; cp < 8; cp++) {
      int c = chgrp * 16 + cp * 2;
      u32 pk = h2bits(__floats2half2_rn(p1v[cp * 2], p1v[cp * 2 + 1]));
      *(u32*)(smem + prow * 768 + ((c * 2) ^ ((prow & 15) << 4))) = pk;
    }
  }
  __syncthreads();   // B ready

  f32x4 acc[2][4];
  #pragma unroll
  for (int i = 0; i < 2; i++)
    #pragma unroll
    for (int j = 0; j < 4; j++) acc[i][j] = (f32x4)0.f;

  // ---- K-loop: barrier-free. afr from global (L2), bfr from LDS ----
  for (int ks = 0; ks < 12; ks++) {
    f16x8 bfr[4], afr[2];
    #pragma unroll
    for (int i = 0; i < 2; i++)
      afr[i] = *(const f16x8*)(W1pk + (size_t)(((wid * 2 + i) * 12 + ks) * 64 + l) * 8);
    #pragma unroll
    for (int j = 0; j < 4; j++) {
      int rb = j * 16 + llo;
      bfr[j] = *(const f16x8*)(smem + rb * 768 + ((ks * 64 + lhi * 16) ^ ((rb & 15) << 4)));
    }
    #pragma unroll
    for (int i = 0; i < 2; i++)
      #pragma unroll
      for (int j = 0; j < 4; j++)
        acc[i][j] = __builtin_amdgcn_mfma_f32_16x16x32_f16(afr[i], bfr[j], acc[i][j], 0, 0, 0);
  }
  __syncthreads();   // all waves done reading B; smem reusable for out-tile

  // ---- epilogue: bias + stats + n-major out-LDS (64 n x 512B) ----
  #pragma unroll
  for (int i = 0; i < 2; i++) {
    int mloc = wid * 32 + i * 16 + lhi * 4;
    float b0 = bias[mloc], b1 = bias[mloc + 1], b2 = bias[mloc + 2], b3 = bias[mloc + 3];
    float s0 = 0, s1 = 0, s2 = 0, s3 = 0, q0 = 0, q1 = 0, q2 = 0, q3 = 0;
    int slotb = (mloc * 2) & ~15, off8 = (mloc * 2) & 15;
    #pragma unroll
    for (int j = 0; j < 4; j++) {
      int n = j * 16 + llo;
      float v0 = acc[i][j][0] + b0;
      float v1 = acc[i][j][1] + b1;
      float v2 = acc[i][j][2] + b2;
      float v3 = acc[i][j][3] + b3;
      s0 += v0; q0 += v0 * v0;
      s1 += v1; q1 += v1 * v1;
      s2 += v2; q2 += v2 * v2;
      s3 += v3; q3 += v3 * v3;
      int base = n * 512 + (slotb ^ ((n & 7) << 4)) + off8;
      *(u32*)(smem + base) = h2bits(__floats2half2_rn(v0, v1));
      *(u32*)(smem + base + 4) = h2bits(__floats2half2_rn(v2, v3));
    }
    #pragma unroll
    for (int off = 1; off < 16; off <<= 1) {
      s0 += __shfl_xor(s0, off, 64); q0 += __shfl_xor(q0, off, 64);
      s1 += __shfl_xor(s1, off, 64); q1 += __shfl_xor(q1, off, 64);
      s2 += __shfl_xor(s2, off, 64); q2 += __shfl_xor(q2, off, 64);
      s3 += __shfl_xor(s3, off, 64); q3 += __shfl_xor(q3, off, 64);
    }
    if (llo == 0) {
      atomicAdd(&sumw[g * 256 + mloc], s0);     atomicAdd(&sqw[g * 256 + mloc], q0);
      atomicAdd(&sumw[g * 256 + mloc + 1], s1); atomicAdd(&sqw[g * 256 + mloc + 1], q1);
      atomicAdd(&sumw[g * 256 + mloc + 2], s2); atomicAdd(&sqw[g * 256 + mloc + 2], q2);
      atomicAdd(&sumw[g * 256 + mloc + 3], s3); atomicAdd(&sqw[g * 256 + mloc + 3], q3);
    }
  }
  __syncthreads();
  {
    int rn = t >> 3, cq = t & 7;
    u16* yrow = Y1 + ((size_t)bg * 4096 + n0 + rn) * 256;
    #pragma unroll
    for (int u = 0; u < 4; u++) {
      int s = u * 8 + cq;
      uint4 v = *(const uint4*)(smem + rn * 512 + ((s * 16) ^ ((rn & 7) << 4)));
      *(uint4*)(yrow + s * 8) = v;
    }
  }
}

// ---------------- BN finalize ----------------
__global__ void bnfin_kernel(const float* __restrict__ sum, const float* __restrict__ sq,
                             const float* __restrict__ gamma, const float* __restrict__ beta,
                             float2* __restrict__ ss, u32* __restrict__ scpk, u32* __restrict__ shpk)
{
  __shared__ float scl[256], shl[256];
  int g = blockIdx.x, m = threadIdx.x;
  int i = g * 256 + m;
  float mean = sum[i] * (1.f / 8192.f);
  float var = sq[i] * (1.f / 8192.f) - mean * mean;
  var = fmaxf(var, 0.f);
  float rstd = rsqrtf(var + 1e-5f);
  float sc = gamma[m] * rstd;
  float sh = beta[m] - mean * sc;
  if (ss) ss[i] = make_float2(sc, sh);
  if (scpk) {
    scl[m] = sc; shl[m] = sh;
    __syncthreads();
    if (m < 128) {
      scpk[g * 128 + m] = h2bits(__floats2half2_rn(scl[2 * m], scl[2 * m + 1]));
      shpk[g * 128 + m] = h2bits(__floats2half2_rn(shl[2 * m], shl[2 * m + 1]));
    }
  }
}

// ================= GEMM2: 512 thr (8 waves x 32m), M=256 x N=64, K=256 (R11) =================
__launch_bounds__(512, 6)
__global__ void gemm2_kernel(const u16* __restrict__ W2pk, const u16* __restrict__ Y1,
                             const u32* __restrict__ scpk, const u32* __restrict__ shpk,
                             const float* __restrict__ bias,
                             float* __restrict__ sumw, float* __restrict__ sqw,
                             u16* __restrict__ Y2)
{
  __shared__ __align__(16) char smem[33792];
  int bx = blockIdx.x;
  int bg = bx >> 6, nt = bx & 63;
  int b = bg >> 4, g = bg & 15;
  int n0 = nt * 64;
  int t = threadIdx.x, wid = t >> 6, l = t & 63;
  int llo = l & 15, lhi = l >> 4;

  if (t < 128) {
    *(u32*)(smem + 32768 + t * 4) = scpk[g * 128 + t];
    *(u32*)(smem + 33280 + t * 4) = shpk[g * 128 + t];
  }

  // ---- B-build: relu(bn1(Y1)) f16, 1 row per 8 threads ----
  {
    int rn = t >> 3, qq = t & 7;
    const u16* yrow = Y1 + ((size_t)bg * 4096 + n0 + rn) * 256;
    uint4 sreg[4];
    #pragma unroll
    for (int u = 0; u < 4; u++) sreg[u] = *(const uint4*)(yrow + (qq * 4 + u) * 8);
    __syncthreads();   // params visible
    const u32* scp = (const u32*)(smem + 32768);
    const u32* shp = (const u32*)(smem + 33280);
    #pragma unroll
    for (int u = 0; u < 4; u++) {
      int s = qq * 4 + u;
      const u32* yw = (const u32*)&sreg[u];
      uint4 o;
      u32* ow = (u32*)&o;
      #pragma unroll
      for (int w = 0; w < 4; w++) {
        int pairi = s * 4 + w;
        __half2 v = __hfma2(bits2h(yw[w]), bits2h(scp[pairi]), bits2h(shp[pairi]));
        ow[w] = pkmax0(h2bits(v));
      }
      *(uint4*)(smem + rn * 512 + ((s * 16) ^ ((rn & 15) << 4))) = o;
    }
  }
  __syncthreads();   // B ready

  f32x4 acc[2][4];
  #pragma unroll
  for (int i = 0; i < 2; i++)
    #pragma unroll
    for (int j = 0; j < 4; j++) acc[i][j] = (f32x4)0.f;

  for (int ks = 0; ks < 8; ks++) {
    f16x8 bfr[4], afr[2];
    #pragma unroll
    for (int i = 0; i < 2; i++)
      afr[i] = *(const f16x8*)(W2pk + (size_t)(((wid * 2 + i) * 8 + ks) * 64 + l) * 8);
    #pragma unroll
    for (int j = 0; j < 4; j++) {
      int rb = j * 16 + llo;
      bfr[j] = *(const f16x8*)(smem + rb * 512 + ((ks * 64 + lhi * 16) ^ ((rb & 15) << 4)));
    }
    #pragma unroll
    for (int i = 0; i < 2; i++)
      #pragma unroll
      for (int j = 0; j < 4; j++)
        acc[i][j] = __builtin_amdgcn_mfma_f32_16x16x32_f16(afr[i], bfr[j], acc[i][j], 0, 0, 0);
  }
  __syncthreads();   // all waves done reading B; smem reusable for out-tile

  // ---- epilogue: bias + stats + m-major out-LDS (256m x 128B) ----
  #pragma unroll
  for (int i = 0; i < 2; i++) {
    int mloc = wid * 32 + i * 16 + lhi * 4;
    float b0 = bias[mloc], b1 = bias[mloc + 1], b2 = bias[mloc + 2], b3 = bias[mloc + 3];
    float s0 = 0, s1 = 0, s2 = 0, s3 = 0, q0 = 0, q1 = 0, q2 = 0, q3 = 0;
    #pragma unroll
    for (int j = 0; j < 4; j++) {
      int n = j * 16 + llo;
      int slotn = (n >> 3) * 16, offn = (n * 2) & 15;
      float v0 = acc[i][j][0] + b0;
      float v1 = acc[i][j][1] + b1;
      float v2 = acc[i][j][2] + b2;
      float v3 = acc[i][j][3] + b3;
      s0 += v0; q0 += v0 * v0;
      s1 += v1; q1 += v1 * v1;
      s2 += v2; q2 += v2 * v2;
      s3 += v3; q3 += v3 * v3;
      *(u16*)(smem + (mloc + 0) * 128 + (slotn ^ (((mloc + 0) & 7) << 4)) + offn) =
          __half_as_ushort(__float2half_rn(v0));
      *(u16*)(smem + (mloc + 1) * 128 + (slotn ^ (((mloc + 1) & 7) << 4)) + offn) =
          __half_as_ushort(__float2half_rn(v1));
      *(u16*)(smem + (mloc + 2) * 128 + (slotn ^ (((mloc + 2) & 7) << 4)) + offn) =
          __half_as_ushort(__float2half_rn(v2));
      *(u16*)(smem + (mloc + 3) * 128 + (slotn ^ (((mloc + 3) & 7) << 4)) + offn) =
          __half_as_ushort(__float2half_rn(v3));
    }
    #pragma unroll
    for (int off = 1; off < 16; off <<= 1) {
      s0 += __shfl_xor(s0, off, 64); q0 += __shfl_xor(q0, off, 64);
      s1 += __shfl_xor(s1, off, 64); q1 += __shfl_xor(q1, off, 64);
      s2 += __shfl_xor(s2, off, 64); q2 += __shfl_xor(q2, off, 64);
      s3 += __shfl_xor(s3, off, 64); q3 += __shfl_xor(q3, off, 64);
    }
    if (llo == 0) {
      atomicAdd(&sumw[g * 256 + mloc], s0);     atomicAdd(&sqw[g * 256 + mloc], q0);
      atomicAdd(&sumw[g * 256 + mloc + 1], s1); atomicAdd(&sqw[g * 256 + mloc + 1], q1);
      atomicAdd(&sumw[g * 256 + mloc + 2], s2); atomicAdd(&sqw[g * 256 + mloc + 2], q2);
      atomicAdd(&sumw[g * 256 + mloc + 3], s3); atomicAdd(&sqw[g * 256 + mloc + 3], q3);
    }
  }
  __syncthreads();
  {
    int mr = t >> 1, hh = t & 1;
    u16* yrow = Y2 + ((size_t)b * 256 + mr) * (size_t)GN_ + (size_t)g * N_ + n0;
    #pragma unroll
    for (int u = 0; u < 4; u++) {
      int s = hh * 4 + u;
      uint4 v = *(const uint4*)(smem + mr * 128 + ((s * 16) ^ ((mr & 7) << 4)));
      *(uint4*)(yrow + s * 8) = v;
    }
  }
}

// ---------------- BN apply 2: Out = relu(bn2(Y2)), f16 -> f32 ----------------
__launch_bounds__(256)
__global__ void bnapply2_kernel(const u16* __restrict__ Y2, const float2* __restrict__ ss,
                                float* __restrict__ Out)
{
  int f8 = blockIdx.x * 256 + threadIdx.x;
  size_t base = (size_t)f8 * 8;
  int m = (int)((base >> 16) & 255);
  int g = (int)((base >> 12) & 15);
  float2 sc = ss[g * 256 + m];
  uint4 yv = *(const uint4*)(Y2 + base);
  const u32* yw = (const u32*)&yv;
  float4 a, b4;
  float* av = (float*)&a;
  float* bvv = (float*)&b4;
  #pragma unroll
  for (int i = 0; i < 2; i++) {
    float2 f = __half22float2(bits2h(yw[i]));
    av[2 * i]     = fmaxf(fmaf(f.x, sc.x, sc.y), 0.f);
    av[2 * i + 1] = fmaxf(fmaf(f.y, sc.x, sc.y), 0.f);
  }
  #pragma unroll
  for (int i = 0; i < 2; i++) {
    float2 f = __half22float2(bits2h(yw[2 + i]));
    bvv[2 * i]     = fmaxf(fmaf(f.x, sc.x, sc.y), 0.f);
    bvv[2 * i + 1] = fmaxf(fmaf(f.y, sc.x, sc.y), 0.f);
  }
  *(float4*)(Out + base) = a;
  *(float4*)(Out + base + 4) = b4;
}

// ---------------- launch ----------------
extern "C" void kernel_launch(void* const* d_in, const int* in_sizes, int n_in,
                              void* d_out, int out_size, void* d_ws, size_t ws_size,
                              hipStream_t stream)
{
  (void)in_sizes; (void)n_in; (void)out_size; (void)ws_size;
  const float* xyz1    = (const float*)d_in[0];
  const float* points1 = (const float*)d_in[1];
  const float* xyz2    = (const float*)d_in[3];
  const float* points2 = (const float*)d_in[4];
  const float* W1      = (const float*)d_in[6];
  const float* b1      = (const float*)d_in[7];
  const float* gamma1  = (const float*)d_in[8];
  const float* beta1   = (const float*)d_in[9];
  const float* W2      = (const float*)d_in[10];
  const float* b2      = (const float*)d_in[11];
  const float* gamma2  = (const float*)d_in[12];
  const float* beta2   = (const float*)d_in[13];
  float* out = (float*)d_out;
  char* ws = (char*)d_ws;

  u16*    W1pk  = (u16*)(ws + OFF_W1PK);
  u16*    W2pk  = (u16*)(ws + OFF_W2PK);
  float4* xyz2p = (float4*)(ws + OFF_XYZ2P);
  float*  sum1  = (float*)(ws + OFF_SUM1);
  float*  sq1   = (float*)(ws + OFF_SQ1);
  float*  sum2  = (float*)(ws + OFF_SUM2);
  float*  sq2   = (float*)(ws + OFF_SQ2);
  u32*    scpk1 = (u32*)(ws + OFF_SCPK1);
  u32*    shpk1 = (u32*)(ws + OFF_SHPK1);
  float2* ss2   = (float2*)(ws + OFF_SS2);
  u16*    p2T   = (u16*)(ws + OFF_P2T);
  u16*    Y2    = (u16*)(ws + OFF_Y2);
  u16*    Y1    = (u16*)(ws + OFF_Y1);

  prep_kernel<<<176, 256, 0, stream>>>(W1, W2, xyz2, W1pk, W2pk, xyz2p, sum1);
  t2_kernel<<<2048, 256, 0, stream>>>(points2, p2T);
  gemm1_kernel<<<2048, 512, 0, stream>>>(W1pk, points1, p2T, xyz1, xyz2p, b1, sum1, sq1, Y1);
  bnfin_kernel<<<16, 256, 0, stream>>>(sum1, sq1, gamma1, beta1, nullptr, scpk1, shpk1);
  gemm2_kernel<<<2048, 512, 0, stream>>>(W2pk, Y1, scpk1, shpk1, b2, sum2, sq2, Y2);
  bnfin_kernel<<<16, 256, 0, stream>>>(sum2, sq2, gamma2, beta2, ss2, nullptr, nullptr);
  bnapply2_kernel<<<16384, 256, 0, stream>>>(Y2, ss2, out);
}

// Round 17
// 242.766 us; speedup vs baseline: 1.0211x; 1.0211x over previous
//
#include <hip/hip_runtime.h>
#include <hip/hip_bf16.h>
#include <hip/hip_fp16.h>

// Problem constants
#define B_    2
#define G_    16
#define N_    4096
#define S_    1024
#define D1_   128
#define D2_   256
#define CIN_  384
#define BG_   32
#define GN_   65536
#define GS_   16384

typedef unsigned int u32;
typedef unsigned short u16;
typedef _Float16 f16x8 __attribute__((ext_vector_type(8)));
typedef float f32x4 __attribute__((ext_vector_type(4)));

__device__ __forceinline__ u32 h2bits(__half2 h) { union { __half2 h; u32 u; } c; c.h = h; return c.u; }
__device__ __forceinline__ __half2 bits2h(u32 u) { union { __half2 h; u32 u; } c; c.u = u; return c.h; }
__device__ __forceinline__ u32 pkmax0(u32 v) {
  u32 r; asm("v_pk_max_f16 %0, %1, %2" : "=v"(r) : "v"(v), "v"(0)); return r;
}

// ---------------- workspace layout (bytes) ----------------
#define OFF_W1PK   0u           // 256*384*2 fragment-packed
#define OFF_W2PK   196608u      // 256*256*2 fragment-packed
#define OFF_XYZ2P  327680u      // 32*256*4*16
#define OFF_SUM1   851968u      // 4 x 16KB contiguous (sum1,sq1,sum2,sq2)
#define OFF_SQ1    868352u
#define OFF_SUM2   884736u
#define OFF_SQ2    901120u
#define OFF_SCPK1  917504u      // 16*128*4 packed half2 scale (BN1)
#define OFF_SHPK1  925696u      // packed half2 shift (BN1)
#define OFF_SS2    950272u      // float2 (BN2)
#define OFF_P2T    5177344u     // 32*1024*256*2 f16
#define OFF_Y2     21954560u    // f16 pre-BN2, OUT layout [b][m][gn]
#define OFF_Y1     122617856u   // f16 pre-BN1, [bg*4096+n][256]

// ---------------- prep: pack weights into MFMA-fragment order, zero stats, pack xyz2 ----------------
__launch_bounds__(256)
__global__ void prep_kernel(const float* __restrict__ W1, const float* __restrict__ W2,
                            const float* __restrict__ xyz2,
                            u16* __restrict__ W1pk, u16* __restrict__ W2pk,
                            float4* __restrict__ xyz2p, float* __restrict__ zeros)
{
  int idx = blockIdx.x * 256 + threadIdx.x;
  if (idx < 12288) {          // W1 fragments
    int lane = idx & 63, ks = (idx >> 6) % 12, mr = idx / (64 * 12);
    int m = mr * 16 + (lane & 15), k = ks * 32 + (lane >> 4) * 8;
    const float* src = W1 + (size_t)m * 384 + k;
    u16* dst = W1pk + (size_t)idx * 8;
    #pragma unroll
    for (int e = 0; e < 8; e++) dst[e] = __half_as_ushort(__float2half_rn(src[e]));
    return;
  }
  idx -= 12288;
  if (idx < 8192) {           // W2 fragments
    int lane = idx & 63, ks = (idx >> 6) % 8, mr = idx / (64 * 8);
    int m = mr * 16 + (lane & 15), k = ks * 32 + (lane >> 4) * 8;
    const float* src = W2 + (size_t)m * 256 + k;
    u16* dst = W2pk + (size_t)idx * 8;
    #pragma unroll
    for (int e = 0; e < 8; e++) dst[e] = __half_as_ushort(__float2half_rn(src[e]));
    return;
  }
  idx -= 8192;
  if (idx < 16384) { zeros[idx] = 0.f; return; }
  idx -= 16384;
  int bg = idx >> 8, q = idx & 255;
  int b = bg >> 4, g = bg & 15;
  const float* base = xyz2 + (size_t)b * 3 * GS_ + (size_t)g * S_ + q * 4;
  float4 X = *(const float4*)(base);
  float4 Y = *(const float4*)(base + GS_);
  float4 Z = *(const float4*)(base + 2 * GS_);
  float4 M;
  M.x = X.x*X.x + Y.x*Y.x + Z.x*Z.x;
  M.y = X.y*X.y + Y.y*Y.y + Z.y*Z.y;
  M.z = X.z*X.z + Y.z*Y.z + Z.z*Z.z;
  M.w = X.w*X.w + Y.w*Y.w + Z.w*Z.w;
  float4* dst = xyz2p + (size_t)idx * 4;
  dst[0] = X; dst[1] = Y; dst[2] = Z; dst[3] = M;
}

// ---------------- transpose points2 -> p2T [s][256] f16 ----------------
__launch_bounds__(256)
__global__ void t2_kernel(const float* __restrict__ p2, u16* __restrict__ p2T)
{
  __shared__ float tl[64][65];
  int bx = blockIdx.x;
  int bg = bx >> 6, r = bx & 63;
  int ct = r >> 4, st = r & 15;
  int c0 = ct * 64, s0 = st * 64;
  int b = bg >> 4, g = bg & 15;
  int t = threadIdx.x, lane = t & 63, w = t >> 6;
  const float* src = p2 + (size_t)b * D2_ * GS_ + (size_t)g * S_ + s0 + lane;
  #pragma unroll
  for (int i = 0; i < 16; i++) {
    int row = w * 16 + i;
    tl[row][lane] = src[(size_t)(c0 + row) * GS_];
  }
  __syncthreads();
  int cp = t & 31, sr = t >> 5;
  #pragma unroll
  for (int i = 0; i < 8; i++) {
    int sl = sr * 8 + i;
    u32 v = h2bits(__floats2half2_rn(tl[2 * cp][sl], tl[2 * cp + 1][sl]));
    *(u32*)(p2T + (((size_t)bg * 1024 + s0 + sl) * 256 + c0 + 2 * cp)) = v;
  }
}

// ================= GEMM1 (fused kNN, wave-uniform): 512 thr, M=256 x N=64, K=384 =========
// Phase 0: kNN for this block's 64 queries. lane(t&63)=query, wave(t>>6)=source-eighth
// -> xp reads are WAVE-UNIFORM (SALU+broadcast, as in the fast standalone knn).
// Merge 8 partials via LDS in ascending-eighth order (strict <, R8 tie semantics).
// Then R11 structure: B 64x768B XOR((r&15)<<4) (49152), barrier-free K-loop, out-tile reuses B.
__launch_bounds__(512, 6)
__global__ void gemm1_kernel(const u16* __restrict__ W1pk, const float* __restrict__ points1,
                             const u16* __restrict__ p2T, const float* __restrict__ xyz1,
                             const float4* __restrict__ xyz2p,
                             const float* __restrict__ bias,
                             float* __restrict__ sumw, float* __restrict__ sqw,
                             u16* __restrict__ Y1)
{
  __shared__ __align__(16) char smem[49152];
  int bx = blockIdx.x;
  int bg = bx >> 6, nt = bx & 63;
  int b = bg >> 4, g = bg & 15;
  int n0 = nt * 64;
  int t = threadIdx.x, wid = t >> 6, l = t & 63;
  int llo = l & 15, lhi = l >> 4;

  // ---- fused kNN: query = l, source-eighth = wid (wave-uniform xp addressing) ----
  {
    const float* x1b = xyz1 + (size_t)b * 3 * GN_ + (size_t)g * N_ + n0 + l;
    float x = x1b[0], y = x1b[GN_], z = x1b[2 * GN_];
    const float4* xp = xyz2p + (size_t)bg * 1024;
    float d0 = 3.4e38f, d1 = 3.4e38f, d2 = 3.4e38f;
    int i0 = 0, i1 = 0, i2 = 0;
    for (int k = 0; k < 32; k++) {
      int q = wid * 32 + k;              // wave-uniform quad index
      float4 X = xp[q * 4 + 0], Y = xp[q * 4 + 1], Z = xp[q * 4 + 2], M = xp[q * 4 + 3];
      const float* Xa = (const float*)&X;
      const float* Ya = (const float*)&Y;
      const float* Za = (const float*)&Z;
      const float* Ma = (const float*)&M;
      #pragma unroll
      for (int u = 0; u < 4; u++) {
        float cr = x * Xa[u];
        cr = fmaf(y, Ya[u], cr);
        cr = fmaf(z, Za[u], cr);
        float d = fmaf(-2.f, cr, Ma[u]); // biased by -|x1|^2; consistent within a query
        int s = q * 4 + u;
        bool cc2 = d < d2, cc1 = d < d1, cc0 = d < d0;
        d2 = cc1 ? d1 : (cc2 ? d : d2);  i2 = cc1 ? i1 : (cc2 ? s : i2);
        d1 = cc0 ? d0 : (cc1 ? d : d1);  i1 = cc0 ? i0 : (cc1 ? s : i1);
        d0 = cc0 ? d : d0;               i0 = cc0 ? s : i0;
      }
    }
    float* sd = (float*)smem;            // [3][512] = 6144 B
    int*   si = (int*)(smem + 6144);     // [3][512] = 6144 B
    sd[0 * 512 + t] = d0; sd[1 * 512 + t] = d1; sd[2 * 512 + t] = d2;
    si[0 * 512 + t] = i0; si[1 * 512 + t] = i1; si[2 * 512 + t] = i2;
    __syncthreads();
    if (t < 64) {                        // wid==0 thread merges eighths 1..7 for query t
      float D0 = d0, D1 = d1, D2 = d2;
      int I0 = i0, I1 = i1, I2 = i2;
      #pragma unroll
      for (int e = 1; e < 8; e++) {
        int idx = e * 64 + t;
        #pragma unroll
        for (int c = 0; c < 3; c++) {
          float d = sd[c * 512 + idx];
          int s = si[c * 512 + idx];
          bool cc0 = d < D0, cc1 = d < D1, cc2 = d < D2;
          I2 = cc1 ? I1 : (cc2 ? s : I2);  D2 = cc1 ? D1 : (cc2 ? d : D2);
          I1 = cc0 ? I0 : (cc1 ? s : I1);  D1 = cc0 ? D0 : (cc1 ? d : D1);
          I0 = cc0 ? s : I0;               D0 = cc0 ? d : D0;
        }
      }
      float m1 = x * x + y * y + z * z;
      float t0 = fmaxf(D0 + m1, 0.f), t1 = fmaxf(D1 + m1, 0.f), t2v = fmaxf(D2 + m1, 0.f);
      float w0 = 1.f / (t0 + 1e-8f);
      float w1 = 1.f / (t1 + 1e-8f);
      float w2 = 1.f / (t2v + 1e-8f);
      float inv = 1.f / (w0 + w1 + w2);
      uint4 rec;
      rec.x = h2bits(__floats2half2_rn(w0 * inv, w1 * inv));
      rec.y = (u32)__half_as_ushort(__float2half_rn(w2 * inv));
      rec.z = (u32)I0 | ((u32)I1 << 16);
      rec.w = (u32)I2;
      *(uint4*)(smem + 12288 + t * 16) = rec;
    }
    __syncthreads();
  }
  uint4 kp = *(const uint4*)(smem + 12288 + (t >> 3) * 16);  // rec for B-build row t>>3
  __syncthreads();   // all kp in regs; smem free for B-tile

  int qr = t >> 3, c8 = t & 7;            // B-build row, channel-eighth

  // ---- B-build: interp ch 128..383, 1 row per 8 threads, 4 chunks each ----
  {
    const u16* p2b = p2T + (size_t)bg * 1024 * 256;
    __half2 w0 = __half2half2(__low2half(bits2h(kp.x)));
    __half2 w1 = __half2half2(__high2half(bits2h(kp.x)));
    __half2 w2 = __half2half2(__low2half(bits2h(kp.y)));
    int i0 = kp.z & 0xffff, i1 = kp.z >> 16, i2 = kp.w & 0xffff;
    const u16* r0 = p2b + (size_t)i0 * 256;
    const u16* r1 = p2b + (size_t)i1 * 256;
    const u16* r2 = p2b + (size_t)i2 * 256;
    #pragma unroll
    for (int u = 0; u < 4; u++) {
      int ch = c8 + 8 * u;
      uint4 q0 = *(const uint4*)(r0 + ch * 8);
      uint4 q1 = *(const uint4*)(r1 + ch * 8);
      uint4 q2 = *(const uint4*)(r2 + ch * 8);
      const u32* a0 = (const u32*)&q0;
      const u32* a1 = (const u32*)&q1;
      const u32* a2 = (const u32*)&q2;
      uint4 o;
      u32* ow = (u32*)&o;
      #pragma unroll
      for (int w = 0; w < 4; w++) {
        __half2 v = __hmul2(w2, bits2h(a2[w]));
        v = __hfma2(w1, bits2h(a1[w]), v);
        v = __hfma2(w0, bits2h(a0[w]), v);
        ow[w] = h2bits(v);
      }
      *(uint4*)(smem + qr * 768 + ((256 + ch * 16) ^ ((qr & 15) << 4))) = o;
    }
    // p1 ch 0..127 transpose: thread owns row (t&63), 16 channels
    int row = t & 63, chgrp = t >> 6;
    const float* p1c = points1 + ((size_t)b * 128 + chgrp * 16) * (size_t)GN_
                     + (size_t)g * N_ + n0 + row;
    #pragma unroll
    for (int cp = 0; cp < 8; cp++) {
      int c = chgrp * 16 + cp * 2;
      u32 pk = h2bits(__floats2half2_rn(p1c[(size_t)(cp * 2) * GN_],
                                        p1c[(size_t)(cp * 2 + 1) * GN_]));
      *(u32*)(smem + row * 768 + ((c * 2) ^ ((row & 15) << 4))) = pk;
    }
  }
  __syncthreads();   // B ready

  f32x4 acc[2][4];
  #pragma unroll
  for (int i = 0; i < 2; i++)
    #pragma unroll
    for (int j = 0; j < 4; j++) acc[i][j] = (f32x4)0.f;

  // ---- K-loop: barrier-free. afr from global (L2), bfr from LDS ----
  for (int ks = 0; ks < 12; ks++) {
    f16x8 bfr[4], afr[2];
    #pragma unroll
    for (int i = 0; i < 2; i++)
      afr[i] = *(const f16x8*)(W1pk + (size_t)(((wid * 2 + i) * 12 + ks) * 64 + l) * 8);
    #pragma unroll
    for (int j = 0; j < 4; j++) {
      int rb = j * 16 + llo;
      bfr[j] = *(const f16x8*)(smem + rb * 768 + ((ks * 64 + lhi * 16) ^ ((rb & 15) << 4)));
    }
    #pragma unroll
    for (int i = 0; i < 2; i++)
      #pragma unroll
      for (int j = 0; j < 4; j++)
        acc[i][j] = __builtin_amdgcn_mfma_f32_16x16x32_f16(afr[i], bfr[j], acc[i][j], 0, 0, 0);
  }
  __syncthreads();   // all waves done reading B; smem reusable for out-tile

  // ---- epilogue: bias + stats + n-major out-LDS (64 n x 512B) ----
  #pragma unroll
  for (int i = 0; i < 2; i++) {
    int mloc = wid * 32 + i * 16 + lhi * 4;
    float b0 = bias[mloc], b1 = bias[mloc + 1], b2 = bias[mloc + 2], b3 = bias[mloc + 3];
    float s0 = 0, s1 = 0, s2 = 0, s3 = 0, q0 = 0, q1 = 0, q2 = 0, q3 = 0;
    int slotb = (mloc * 2) & ~15, off8 = (mloc * 2) & 15;
    #pragma unroll
    for (int j = 0; j < 4; j++) {
      int n = j * 16 + llo;
      float v0 = acc[i][j][0] + b0;
      float v1 = acc[i][j][1] + b1;
      float v2 = acc[i][j][2] + b2;
      float v3 = acc[i][j][3] + b3;
      s0 += v0; q0 += v0 * v0;
      s1 += v1; q1 += v1 * v1;
      s2 += v2; q2 += v2 * v2;
      s3 += v3; q3 += v3 * v3;
      int base = n * 512 + (slotb ^ ((n & 7) << 4)) + off8;
      *(u32*)(smem + base) = h2bits(__floats2half2_rn(v0, v1));
      *(u32*)(smem + base + 4) = h2bits(__floats2half2_rn(v2, v3));
    }
    #pragma unroll
    for (int off = 1; off < 16; off <<= 1) {
      s0 += __shfl_xor(s0, off, 64); q0 += __shfl_xor(q0, off, 64);
      s1 += __shfl_xor(s1, off, 64); q1 += __shfl_xor(q1, off, 64);
      s2 += __shfl_xor(s2, off, 64); q2 += __shfl_xor(q2, off, 64);
      s3 += __shfl_xor(s3, off, 64); q3 += __shfl_xor(q3, off, 64);
    }
    if (llo == 0) {
      atomicAdd(&sumw[g * 256 + mloc], s0);     atomicAdd(&sqw[g * 256 + mloc], q0);
      atomicAdd(&sumw[g * 256 + mloc + 1], s1); atomicAdd(&sqw[g * 256 + mloc + 1], q1);
      atomicAdd(&sumw[g * 256 + mloc + 2], s2); atomicAdd(&sqw[g * 256 + mloc + 2], q2);
      atomicAdd(&sumw[g * 256 + mloc + 3], s3); atomicAdd(&sqw[g * 256 + mloc + 3], q3);
    }
  }
  __syncthreads();
  {
    int rn = t >> 3, cq = t & 7;
    u16* yrow = Y1 + ((size_t)bg * 4096 + n0 + rn) * 256;
    #pragma unroll
    for (int u = 0; u < 4; u++) {
      int s = u * 8 + cq;
      uint4 v = *(const uint4*)(smem + rn * 512 + ((s * 16) ^ ((rn & 7) << 4)));
      *(uint4*)(yrow + s * 8) = v;
    }
  }
}

// ---------------- BN finalize ----------------
__global__ void bnfin_kernel(const float* __restrict__ sum, const float* __restrict__ sq,
                             const float* __restrict__ gamma, const float* __restrict__ beta,
                             float2* __restrict__ ss, u32* __restrict__ scpk, u32* __restrict__ shpk)
{
  __shared__ float scl[256], shl[256];
  int g = blockIdx.x, m = threadIdx.x;
  int i = g * 256 + m;
  float mean = sum[i] * (1.f / 8192.f);
  float var = sq[i] * (1.f / 8192.f) - mean * mean;
  var = fmaxf(var, 0.f);
  float rstd = rsqrtf(var + 1e-5f);
  float sc = gamma[m] * rstd;
  float sh = beta[m] - mean * sc;
  if (ss) ss[i] = make_float2(sc, sh);
  if (scpk) {
    scl[m] = sc; shl[m] = sh;
    __syncthreads();
    if (m < 128) {
      scpk[g * 128 + m] = h2bits(__floats2half2_rn(scl[2 * m], scl[2 * m + 1]));
      shpk[g * 128 + m] = h2bits(__floats2half2_rn(shl[2 * m], shl[2 * m + 1]));
    }
  }
}

// ================= GEMM2: 512 thr (8 waves x 32m), M=256 x N=64, K=256 (R11) =================
__launch_bounds__(512, 6)
__global__ void gemm2_kernel(const u16* __restrict__ W2pk, const u16* __restrict__ Y1,
                             const u32* __restrict__ scpk, const u32* __restrict__ shpk,
                             const float* __restrict__ bias,
                             float* __restrict__ sumw, float* __restrict__ sqw,
                             u16* __restrict__ Y2)
{
  __shared__ __align__(16) char smem[33792];
  int bx = blockIdx.x;
  int bg = bx >> 6, nt = bx & 63;
  int b = bg >> 4, g = bg & 15;
  int n0 = nt * 64;
  int t = threadIdx.x, wid = t >> 6, l = t & 63;
  int llo = l & 15, lhi = l >> 4;

  if (t < 128) {
    *(u32*)(smem + 32768 + t * 4) = scpk[g * 128 + t];
    *(u32*)(smem + 33280 + t * 4) = shpk[g * 128 + t];
  }

  // ---- B-build: relu(bn1(Y1)) f16, 1 row per 8 threads ----
  {
    int rn = t >> 3, qq = t & 7;
    const u16* yrow = Y1 + ((size_t)bg * 4096 + n0 + rn) * 256;
    uint4 sreg[4];
    #pragma unroll
    for (int u = 0; u < 4; u++) sreg[u] = *(const uint4*)(yrow + (qq * 4 + u) * 8);
    __syncthreads();   // params visible
    const u32* scp = (const u32*)(smem + 32768);
    const u32* shp = (const u32*)(smem + 33280);
    #pragma unroll
    for (int u = 0; u < 4; u++) {
      int s = qq * 4 + u;
      const u32* yw = (const u32*)&sreg[u];
      uint4 o;
      u32* ow = (u32*)&o;
      #pragma unroll
      for (int w = 0; w < 4; w++) {
        int pairi = s * 4 + w;
        __half2 v = __hfma2(bits2h(yw[w]), bits2h(scp[pairi]), bits2h(shp[pairi]));
        ow[w] = pkmax0(h2bits(v));
      }
      *(uint4*)(smem + rn * 512 + ((s * 16) ^ ((rn & 15) << 4))) = o;
    }
  }
  __syncthreads();   // B ready

  f32x4 acc[2][4];
  #pragma unroll
  for (int i = 0; i < 2; i++)
    #pragma unroll
    for (int j = 0; j < 4; j++) acc[i][j] = (f32x4)0.f;

  for (int ks = 0; ks < 8; ks++) {
    f16x8 bfr[4], afr[2];
    #pragma unroll
    for (int i = 0; i < 2; i++)
      afr[i] = *(const f16x8*)(W2pk + (size_t)(((wid * 2 + i) * 8 + ks) * 64 + l) * 8);
    #pragma unroll
    for (int j = 0; j < 4; j++) {
      int rb = j * 16 + llo;
      bfr[j] = *(const f16x8*)(smem + rb * 512 + ((ks * 64 + lhi * 16) ^ ((rb & 15) << 4)));
    }
    #pragma unroll
    for (int i = 0; i < 2; i++)
      #pragma unroll
      for (int j = 0; j < 4; j++)
        acc[i][j] = __builtin_amdgcn_mfma_f32_16x16x32_f16(afr[i], bfr[j], acc[i][j], 0, 0, 0);
  }
  __syncthreads();   // all waves done reading B; smem reusable for out-tile

  // ---- epilogue: bias + stats + m-major out-LDS (256m x 128B) ----
  #pragma unroll
  for (int i = 0; i < 2; i++) {
    int mloc = wid * 32 + i * 16 + lhi * 4;
    float b0 = bias[mloc], b1 = bias[mloc + 1], b2 = bias[mloc + 2], b3 = bias[mloc + 3];
    float s0 = 0, s1 = 0, s2 = 0, s3 = 0, q0 = 0, q1 = 0, q2 = 0, q3 = 0;
    #pragma unroll
    for (int j = 0; j < 4; j++) {
      int n = j * 16 + llo;
      int slotn = (n >> 3) * 16, offn = (n * 2) & 15;
      float v0 = acc[i][j][0] + b0;
      float v1 = acc[i][j][1] + b1;
      float v2 = acc[i][j][2] + b2;
      float v3 = acc[i][j][3] + b3;
      s0 += v0; q0 += v0 * v0;
      s1 += v1; q1 += v1 * v1;
      s2 += v2; q2 += v2 * v2;
      s3 += v3; q3 += v3 * v3;
      *(u16*)(smem + (mloc + 0) * 128 + (slotn ^ (((mloc + 0) & 7) << 4)) + offn) =
          __half_as_ushort(__float2half_rn(v0));
      *(u16*)(smem + (mloc + 1) * 128 + (slotn ^ (((mloc + 1) & 7) << 4)) + offn) =
          __half_as_ushort(__float2half_rn(v1));
      *(u16*)(smem + (mloc + 2) * 128 + (slotn ^ (((mloc + 2) & 7) << 4)) + offn) =
          __half_as_ushort(__float2half_rn(v2));
      *(u16*)(smem + (mloc + 3) * 128 + (slotn ^ (((mloc + 3) & 7) << 4)) + offn) =
          __half_as_ushort(__float2half_rn(v3));
    }
    #pragma unroll
    for (int off = 1; off < 16; off <<= 1) {
      s0 += __shfl_xor(s0, off, 64); q0 += __shfl_xor(q0, off, 64);
      s1 += __shfl_xor(s1, off, 64); q1 += __shfl_xor(q1, off, 64);
      s2 += __shfl_xor(s2, off, 64); q2 += __shfl_xor(q2, off, 64);
      s3 += __shfl_xor(s3, off, 64); q3 += __shfl_xor(q3, off, 64);
    }
    if (llo == 0) {
      atomicAdd(&sumw[g * 256 + mloc], s0);     atomicAdd(&sqw[g * 256 + mloc], q0);
      atomicAdd(&sumw[g * 256 + mloc + 1], s1); atomicAdd(&sqw[g * 256 + mloc + 1], q1);
      atomicAdd(&sumw[g * 256 + mloc + 2], s2); atomicAdd(&sqw[g * 256 + mloc + 2], q2);
      atomicAdd(&sumw[g * 256 + mloc + 3], s3); atomicAdd(&sqw[g * 256 + mloc + 3], q3);
    }
  }
  __syncthreads();
  {
    int mr = t >> 1, hh = t & 1;
    u16* yrow = Y2 + ((size_t)b * 256 + mr) * (size_t)GN_ + (size_t)g * N_ + n0;
    #pragma unroll
    for (int u = 0; u < 4; u++) {
      int s = hh * 4 + u;
      uint4 v = *(const uint4*)(smem + mr * 128 + ((s * 16) ^ ((mr & 7) << 4)));
      *(uint4*)(yrow + s * 8) = v;
    }
  }
}

// ---------------- BN apply 2: Out = relu(bn2(Y2)), f16 -> f32 ----------------
__launch_bounds__(256)
__global__ void bnapply2_kernel(const u16* __restrict__ Y2, const float2* __restrict__ ss,
                                float* __restrict__ Out)
{
  int f8 = blockIdx.x * 256 + threadIdx.x;
  size_t base = (size_t)f8 * 8;
  int m = (int)((base >> 16) & 255);
  int g = (int)((base >> 12) & 15);
  float2 sc = ss[g * 256 + m];
  uint4 yv = *(const uint4*)(Y2 + base);
  const u32* yw = (const u32*)&yv;
  float4 a, b4;
  float* av = (float*)&a;
  float* bvv = (float*)&b4;
  #pragma unroll
  for (int i = 0; i < 2; i++) {
    float2 f = __half22float2(bits2h(yw[i]));
    av[2 * i]     = fmaxf(fmaf(f.x, sc.x, sc.y), 0.f);
    av[2 * i + 1] = fmaxf(fmaf(f.y, sc.x, sc.y), 0.f);
  }
  #pragma unroll
  for (int i = 0; i < 2; i++) {
    float2 f = __half22float2(bits2h(yw[2 + i]));
    bvv[2 * i]     = fmaxf(fmaf(f.x, sc.x, sc.y), 0.f);
    bvv[2 * i + 1] = fmaxf(fmaf(f.y, sc.x, sc.y), 0.f);
  }
  *(float4*)(Out + base) = a;
  *(float4*)(Out + base + 4) = b4;
}

// ---------------- launch ----------------
extern "C" void kernel_launch(void* const* d_in, const int* in_sizes, int n_in,
                              void* d_out, int out_size, void* d_ws, size_t ws_size,
                              hipStream_t stream)
{
  (void)in_sizes; (void)n_in; (void)out_size; (void)ws_size;
  const float* xyz1    = (const float*)d_in[0];
  const float* points1 = (const float*)d_in[1];
  const float* xyz2    = (const float*)d_in[3];
  const float* points2 = (const float*)d_in[4];
  const float* W1      = (const float*)d_in[6];
  const float* b1      = (const float*)d_in[7];
  const float* gamma1  = (const float*)d_in[8];
  const float* beta1   = (const float*)d_in[9];
  const float* W2      = (const float*)d_in[10];
  const float* b2      = (const float*)d_in[11];
  const float* gamma2  = (const float*)d_in[12];
  const float* beta2   = (const float*)d_in[13];
  float* out = (float*)d_out;
  char* ws = (char*)d_ws;

  u16*    W1pk  = (u16*)(ws + OFF_W1PK);
  u16*    W2pk  = (u16*)(ws + OFF_W2PK);
  float4* xyz2p = (float4*)(ws + OFF_XYZ2P);
  float*  sum1  = (float*)(ws + OFF_SUM1);
  float*  sq1   = (float*)(ws + OFF_SQ1);
  float*  sum2  = (float*)(ws + OFF_SUM2);
  float*  sq2   = (float*)(ws + OFF_SQ2);
  u32*    scpk1 = (u32*)(ws + OFF_SCPK1);
  u32*    shpk1 = (u32*)(ws + OFF_SHPK1);
  float2* ss2   = (float2*)(ws + OFF_SS2);
  u16*    p2T   = (u16*)(ws + OFF_P2T);
  u16*    Y2    = (u16*)(ws + OFF_Y2);
  u16*    Y1    = (u16*)(ws + OFF_Y1);

  prep_kernel<<<176, 256, 0, stream>>>(W1, W2, xyz2, W1pk, W2pk, xyz2p, sum1);
  t2_kernel<<<2048, 256, 0, stream>>>(points2, p2T);
  gemm1_kernel<<<2048, 512, 0, stream>>>(W1pk, points1, p2T, xyz1, xyz2p, b1, sum1, sq1, Y1);
  bnfin_kernel<<<16, 256, 0, stream>>>(sum1, sq1, gamma1, beta1, nullptr, scpk1, shpk1);
  gemm2_kernel<<<2048, 512, 0, stream>>>(W2pk, Y1, scpk1, shpk1, b2, sum2, sq2, Y2);
  bnfin_kernel<<<16, 256, 0, stream>>>(sum2, sq2, gamma2, beta2, ss2, nullptr, nullptr);
  bnapply2_kernel<<<16384, 256, 0, stream>>>(Y2, ss2, out);
}

// Round 18
// 225.044 us; speedup vs baseline: 1.1015x; 1.0787x over previous
//
#include <hip/hip_runtime.h>
#include <hip/hip_bf16.h>
#include <hip/hip_fp16.h>

// Problem constants
#define B_    2
#define G_    16
#define N_    4096
#define S_    1024
#define D1_   128
#define D2_   256
#define CIN_  384
#define BG_   32
#define GN_   65536
#define GS_   16384

typedef unsigned int u32;
typedef unsigned short u16;
typedef _Float16 f16x8 __attribute__((ext_vector_type(8)));
typedef float f32x4 __attribute__((ext_vector_type(4)));

__device__ __forceinline__ u32 h2bits(__half2 h) { union { __half2 h; u32 u; } c; c.h = h; return c.u; }
__device__ __forceinline__ __half2 bits2h(u32 u) { union { __half2 h; u32 u; } c; c.u = u; return c.h; }
__device__ __forceinline__ u32 pkmax0(u32 v) {
  u32 r; asm("v_pk_max_f16 %0, %1, %2" : "=v"(r) : "v"(v), "v"(0)); return r;
}

// ---------------- workspace layout (bytes) ----------------
#define OFF_W1PK   0u           // 256*384*2 fragment-packed
#define OFF_W2PK   196608u      // 256*256*2 fragment-packed
#define OFF_XYZ2P  327680u      // 32*256*4*16
#define OFF_SUM1   851968u      // 4 x 16KB contiguous (sum1,sq1,sum2,sq2)
#define OFF_SQ1    868352u
#define OFF_SUM2   884736u
#define OFF_SQ2    901120u
#define OFF_SCPK1  917504u      // 16*128*4 packed half2 scale (BN1)
#define OFF_SHPK1  925696u      // packed half2 shift (BN1)
#define OFF_SS2    950272u      // float2 (BN2)
#define OFF_P2T    5177344u     // 32*1024*256*2 f16
#define OFF_Y2     21954560u    // f16 pre-BN2, OUT layout [b][m][gn]
#define OFF_Y1     122617856u   // f16 pre-BN1, [bg*4096+n][256]

// ---------------- prep: pack weights into MFMA-fragment order, zero stats, pack xyz2 ----------------
__launch_bounds__(256)
__global__ void prep_kernel(const float* __restrict__ W1, const float* __restrict__ W2,
                            const float* __restrict__ xyz2,
                            u16* __restrict__ W1pk, u16* __restrict__ W2pk,
                            float4* __restrict__ xyz2p, float* __restrict__ zeros)
{
  int idx = blockIdx.x * 256 + threadIdx.x;
  if (idx < 12288) {          // W1 fragments
    int lane = idx & 63, ks = (idx >> 6) % 12, mr = idx / (64 * 12);
    int m = mr * 16 + (lane & 15), k = ks * 32 + (lane >> 4) * 8;
    const float* src = W1 + (size_t)m * 384 + k;
    u16* dst = W1pk + (size_t)idx * 8;
    #pragma unroll
    for (int e = 0; e < 8; e++) dst[e] = __half_as_ushort(__float2half_rn(src[e]));
    return;
  }
  idx -= 12288;
  if (idx < 8192) {           // W2 fragments
    int lane = idx & 63, ks = (idx >> 6) % 8, mr = idx / (64 * 8);
    int m = mr * 16 + (lane & 15), k = ks * 32 + (lane >> 4) * 8;
    const float* src = W2 + (size_t)m * 256 + k;
    u16* dst = W2pk + (size_t)idx * 8;
    #pragma unroll
    for (int e = 0; e < 8; e++) dst[e] = __half_as_ushort(__float2half_rn(src[e]));
    return;
  }
  idx -= 8192;
  if (idx < 16384) { zeros[idx] = 0.f; return; }
  idx -= 16384;
  int bg = idx >> 8, q = idx & 255;
  int b = bg >> 4, g = bg & 15;
  const float* base = xyz2 + (size_t)b * 3 * GS_ + (size_t)g * S_ + q * 4;
  float4 X = *(const float4*)(base);
  float4 Y = *(const float4*)(base + GS_);
  float4 Z = *(const float4*)(base + 2 * GS_);
  float4 M;
  M.x = X.x*X.x + Y.x*Y.x + Z.x*Z.x;
  M.y = X.y*X.y + Y.y*Y.y + Z.y*Z.y;
  M.z = X.z*X.z + Y.z*Y.z + Z.z*Z.z;
  M.w = X.w*X.w + Y.w*Y.w + Z.w*Z.w;
  float4* dst = xyz2p + (size_t)idx * 4;
  dst[0] = X; dst[1] = Y; dst[2] = Z; dst[3] = M;
}

// ---------------- transpose points2 -> p2T [s][256] f16 ----------------
__launch_bounds__(256)
__global__ void t2_kernel(const float* __restrict__ p2, u16* __restrict__ p2T)
{
  __shared__ float tl[64][65];
  int bx = blockIdx.x;
  int bg = bx >> 6, r = bx & 63;
  int ct = r >> 4, st = r & 15;
  int c0 = ct * 64, s0 = st * 64;
  int b = bg >> 4, g = bg & 15;
  int t = threadIdx.x, lane = t & 63, w = t >> 6;
  const float* src = p2 + (size_t)b * D2_ * GS_ + (size_t)g * S_ + s0 + lane;
  #pragma unroll
  for (int i = 0; i < 16; i++) {
    int row = w * 16 + i;
    tl[row][lane] = src[(size_t)(c0 + row) * GS_];
  }
  __syncthreads();
  int cp = t & 31, sr = t >> 5;
  #pragma unroll
  for (int i = 0; i < 8; i++) {
    int sl = sr * 8 + i;
    u32 v = h2bits(__floats2half2_rn(tl[2 * cp][sl], tl[2 * cp + 1][sl]));
    *(u32*)(p2T + (((size_t)bg * 1024 + s0 + sl) * 256 + c0 + 2 * cp)) = v;
  }
}

// ================= GEMM1 (fused kNN, wave-uniform): 512 thr, M=256 x N=64, K=384 =========
// Phase 0: kNN for this block's 64 queries. lane(t&63)=query, wave(t>>6)=source-eighth
// -> xp reads WAVE-UNIFORM; q forced to SGPR via readfirstlane so the compiler emits
//    scalar (s_load) reads: zero VALU address math, zero VMEM issue in the hot loop.
// Merge 8 partials via LDS in ascending-eighth order (strict <, R8 tie semantics).
// Then R11 structure: B 64x768B XOR((r&15)<<4) (49152), barrier-free K-loop, out-tile reuses B.
__launch_bounds__(512, 6)
__global__ void gemm1_kernel(const u16* __restrict__ W1pk, const float* __restrict__ points1,
                             const u16* __restrict__ p2T, const float* __restrict__ xyz1,
                             const float4* __restrict__ xyz2p,
                             const float* __restrict__ bias,
                             float* __restrict__ sumw, float* __restrict__ sqw,
                             u16* __restrict__ Y1)
{
  __shared__ __align__(16) char smem[49152];
  int bx = blockIdx.x;
  int bg = bx >> 6, nt = bx & 63;
  int b = bg >> 4, g = bg & 15;
  int n0 = nt * 64;
  int t = threadIdx.x, wid = t >> 6, l = t & 63;
  int llo = l & 15, lhi = l >> 4;

  // ---- fused kNN: query = l, source-eighth = wid (wave-uniform xp addressing) ----
  {
    const float* x1b = xyz1 + (size_t)b * 3 * GN_ + (size_t)g * N_ + n0 + l;
    float x = x1b[0], y = x1b[GN_], z = x1b[2 * GN_];
    const float4* xp = xyz2p + (size_t)bg * 1024;
    float d0 = 3.4e38f, d1 = 3.4e38f, d2 = 3.4e38f;
    int i0 = 0, i1 = 0, i2 = 0;
    for (int k = 0; k < 32; k++) {
      // wave-uniform quad index, FORCED to SGPR -> scalar loads below
      int q = __builtin_amdgcn_readfirstlane(wid * 32 + k);
      float4 X = xp[q * 4 + 0], Y = xp[q * 4 + 1], Z = xp[q * 4 + 2], M = xp[q * 4 + 3];
      const float* Xa = (const float*)&X;
      const float* Ya = (const float*)&Y;
      const float* Za = (const float*)&Z;
      const float* Ma = (const float*)&M;
      #pragma unroll
      for (int u = 0; u < 4; u++) {
        float cr = x * Xa[u];
        cr = fmaf(y, Ya[u], cr);
        cr = fmaf(z, Za[u], cr);
        float d = fmaf(-2.f, cr, Ma[u]); // biased by -|x1|^2; consistent within a query
        int s = q * 4 + u;
        bool cc2 = d < d2, cc1 = d < d1, cc0 = d < d0;
        d2 = cc1 ? d1 : (cc2 ? d : d2);  i2 = cc1 ? i1 : (cc2 ? s : i2);
        d1 = cc0 ? d0 : (cc1 ? d : d1);  i1 = cc0 ? i0 : (cc1 ? s : i1);
        d0 = cc0 ? d : d0;               i0 = cc0 ? s : i0;
      }
    }
    float* sd = (float*)smem;            // [3][512] = 6144 B
    int*   si = (int*)(smem + 6144);     // [3][512] = 6144 B
    sd[0 * 512 + t] = d0; sd[1 * 512 + t] = d1; sd[2 * 512 + t] = d2;
    si[0 * 512 + t] = i0; si[1 * 512 + t] = i1; si[2 * 512 + t] = i2;
    __syncthreads();
    if (t < 64) {                        // wid==0 thread merges eighths 1..7 for query t
      float D0 = d0, D1 = d1, D2 = d2;
      int I0 = i0, I1 = i1, I2 = i2;
      #pragma unroll
      for (int e = 1; e < 8; e++) {
        int idx = e * 64 + t;
        #pragma unroll
        for (int c = 0; c < 3; c++) {
          float d = sd[c * 512 + idx];
          int s = si[c * 512 + idx];
          bool cc0 = d < D0, cc1 = d < D1, cc2 = d < D2;
          I2 = cc1 ? I1 : (cc2 ? s : I2);  D2 = cc1 ? D1 : (cc2 ? d : D2);
          I1 = cc0 ? I0 : (cc1 ? s : I1);  D1 = cc0 ? D0 : (cc1 ? d : D1);
          I0 = cc0 ? s : I0;               D0 = cc0 ? d : D0;
        }
      }
      float m1 = x * x + y * y + z * z;
      float t0 = fmaxf(D0 + m1, 0.f), t1 = fmaxf(D1 + m1, 0.f), t2v = fmaxf(D2 + m1, 0.f);
      float w0 = 1.f / (t0 + 1e-8f);
      float w1 = 1.f / (t1 + 1e-8f);
      float w2 = 1.f / (t2v + 1e-8f);
      float inv = 1.f / (w0 + w1 + w2);
      uint4 rec;
      rec.x = h2bits(__floats2half2_rn(w0 * inv, w1 * inv));
      rec.y = (u32)__half_as_ushort(__float2half_rn(w2 * inv));
      rec.z = (u32)I0 | ((u32)I1 << 16);
      rec.w = (u32)I2;
      *(uint4*)(smem + 12288 + t * 16) = rec;
    }
    __syncthreads();
  }
  uint4 kp = *(const uint4*)(smem + 12288 + (t >> 3) * 16);  // rec for B-build row t>>3
  __syncthreads();   // all kp in regs; smem free for B-tile

  int qr = t >> 3, c8 = t & 7;            // B-build row, channel-eighth

  // ---- B-build: interp ch 128..383, 1 row per 8 threads, 4 chunks each ----
  {
    const u16* p2b = p2T + (size_t)bg * 1024 * 256;
    __half2 w0 = __half2half2(__low2half(bits2h(kp.x)));
    __half2 w1 = __half2half2(__high2half(bits2h(kp.x)));
    __half2 w2 = __half2half2(__low2half(bits2h(kp.y)));
    int i0 = kp.z & 0xffff, i1 = kp.z >> 16, i2 = kp.w & 0xffff;
    const u16* r0 = p2b + (size_t)i0 * 256;
    const u16* r1 = p2b + (size_t)i1 * 256;
    const u16* r2 = p2b + (size_t)i2 * 256;
    #pragma unroll
    for (int u = 0; u < 4; u++) {
      int ch = c8 + 8 * u;
      uint4 q0 = *(const uint4*)(r0 + ch * 8);
      uint4 q1 = *(const uint4*)(r1 + ch * 8);
      uint4 q2 = *(const uint4*)(r2 + ch * 8);
      const u32* a0 = (const u32*)&q0;
      const u32* a1 = (const u32*)&q1;
      const u32* a2 = (const u32*)&q2;
      uint4 o;
      u32* ow = (u32*)&o;
      #pragma unroll
      for (int w = 0; w < 4; w++) {
        __half2 v = __hmul2(w2, bits2h(a2[w]));
        v = __hfma2(w1, bits2h(a1[w]), v);
        v = __hfma2(w0, bits2h(a0[w]), v);
        ow[w] = h2bits(v);
      }
      *(uint4*)(smem + qr * 768 + ((256 + ch * 16) ^ ((qr & 15) << 4))) = o;
    }
    // p1 ch 0..127 transpose: thread owns row (t&63), 16 channels
    int row = t & 63, chgrp = t >> 6;
    const float* p1c = points1 + ((size_t)b * 128 + chgrp * 16) * (size_t)GN_
                     + (size_t)g * N_ + n0 + row;
    #pragma unroll
    for (int cp = 0; cp < 8; cp++) {
      int c = chgrp * 16 + cp * 2;
      u32 pk = h2bits(__floats2half2_rn(p1c[(size_t)(cp * 2) * GN_],
                                        p1c[(size_t)(cp * 2 + 1) * GN_]));
      *(u32*)(smem + row * 768 + ((c * 2) ^ ((row & 15) << 4))) = pk;
    }
  }
  __syncthreads();   // B ready

  f32x4 acc[2][4];
  #pragma unroll
  for (int i = 0; i < 2; i++)
    #pragma unroll
    for (int j = 0; j < 4; j++) acc[i][j] = (f32x4)0.f;

  // ---- K-loop: barrier-free. afr from global (L2), bfr from LDS ----
  for (int ks = 0; ks < 12; ks++) {
    f16x8 bfr[4], afr[2];
    #pragma unroll
    for (int i = 0; i < 2; i++)
      afr[i] = *(const f16x8*)(W1pk + (size_t)(((wid * 2 + i) * 12 + ks) * 64 + l) * 8);
    #pragma unroll
    for (int j = 0; j < 4; j++) {
      int rb = j * 16 + llo;
      bfr[j] = *(const f16x8*)(smem + rb * 768 + ((ks * 64 + lhi * 16) ^ ((rb & 15) << 4)));
    }
    #pragma unroll
    for (int i = 0; i < 2; i++)
      #pragma unroll
      for (int j = 0; j < 4; j++)
        acc[i][j] = __builtin_amdgcn_mfma_f32_16x16x32_f16(afr[i], bfr[j], acc[i][j], 0, 0, 0);
  }
  __syncthreads();   // all waves done reading B; smem reusable for out-tile

  // ---- epilogue: bias + stats + n-major out-LDS (64 n x 512B) ----
  #pragma unroll
  for (int i = 0; i < 2; i++) {
    int mloc = wid * 32 + i * 16 + lhi * 4;
    float b0 = bias[mloc], b1 = bias[mloc + 1], b2 = bias[mloc + 2], b3 = bias[mloc + 3];
    float s0 = 0, s1 = 0, s2 = 0, s3 = 0, q0 = 0, q1 = 0, q2 = 0, q3 = 0;
    int slotb = (mloc * 2) & ~15, off8 = (mloc * 2) & 15;
    #pragma unroll
    for (int j = 0; j < 4; j++) {
      int n = j * 16 + llo;
      float v0 = acc[i][j][0] + b0;
      float v1 = acc[i][j][1] + b1;
      float v2 = acc[i][j][2] + b2;
      float v3 = acc[i][j][3] + b3;
      s0 += v0; q0 += v0 * v0;
      s1 += v1; q1 += v1 * v1;
      s2 += v2; q2 += v2 * v2;
      s3 += v3; q3 += v3 * v3;
      int base = n * 512 + (slotb ^ ((n & 7) << 4)) + off8;
      *(u32*)(smem + base) = h2bits(__floats2half2_rn(v0, v1));
      *(u32*)(smem + base + 4) = h2bits(__floats2half2_rn(v2, v3));
    }
    #pragma unroll
    for (int off = 1; off < 16; off <<= 1) {
      s0 += __shfl_xor(s0, off, 64); q0 += __shfl_xor(q0, off, 64);
      s1 += __shfl_xor(s1, off, 64); q1 += __shfl_xor(q1, off, 64);
      s2 += __shfl_xor(s2, off, 64); q2 += __shfl_xor(q2, off, 64);
      s3 += __shfl_xor(s3, off, 64); q3 += __shfl_xor(q3, off, 64);
    }
    if (llo == 0) {
      atomicAdd(&sumw[g * 256 + mloc], s0);     atomicAdd(&sqw[g * 256 + mloc], q0);
      atomicAdd(&sumw[g * 256 + mloc + 1], s1); atomicAdd(&sqw[g * 256 + mloc + 1], q1);
      atomicAdd(&sumw[g * 256 + mloc + 2], s2); atomicAdd(&sqw[g * 256 + mloc + 2], q2);
      atomicAdd(&sumw[g * 256 + mloc + 3], s3); atomicAdd(&sqw[g * 256 + mloc + 3], q3);
    }
  }
  __syncthreads();
  {
    int rn = t >> 3, cq = t & 7;
    u16* yrow = Y1 + ((size_t)bg * 4096 + n0 + rn) * 256;
    #pragma unroll
    for (int u = 0; u < 4; u++) {
      int s = u * 8 + cq;
      uint4 v = *(const uint4*)(smem + rn * 512 + ((s * 16) ^ ((rn & 7) << 4)));
      *(uint4*)(yrow + s * 8) = v;
    }
  }
}

// ---------------- BN finalize ----------------
__global__ void bnfin_kernel(const float* __restrict__ sum, const float* __restrict__ sq,
                             const float* __restrict__ gamma, const float* __restrict__ beta,
                             float2* __restrict__ ss, u32* __restrict__ scpk, u32* __restrict__ shpk)
{
  __shared__ float scl[256], shl[256];
  int g = blockIdx.x, m = threadIdx.x;
  int i = g * 256 + m;
  float mean = sum[i] * (1.f / 8192.f);
  float var = sq[i] * (1.f / 8192.f) - mean * mean;
  var = fmaxf(var, 0.f);
  float rstd = rsqrtf(var + 1e-5f);
  float sc = gamma[m] * rstd;
  float sh = beta[m] - mean * sc;
  if (ss) ss[i] = make_float2(sc, sh);
  if (scpk) {
    scl[m] = sc; shl[m] = sh;
    __syncthreads();
    if (m < 128) {
      scpk[g * 128 + m] = h2bits(__floats2half2_rn(scl[2 * m], scl[2 * m + 1]));
      shpk[g * 128 + m] = h2bits(__floats2half2_rn(shl[2 * m], shl[2 * m + 1]));
    }
  }
}

// ================= GEMM2: 512 thr (8 waves x 32m), M=256 x N=64, K=256 (R11) =================
__launch_bounds__(512, 6)
__global__ void gemm2_kernel(const u16* __restrict__ W2pk, const u16* __restrict__ Y1,
                             const u32* __restrict__ scpk, const u32* __restrict__ shpk,
                             const float* __restrict__ bias,
                             float* __restrict__ sumw, float* __restrict__ sqw,
                             u16* __restrict__ Y2)
{
  __shared__ __align__(16) char smem[33792];
  int bx = blockIdx.x;
  int bg = bx >> 6, nt = bx & 63;
  int b = bg >> 4, g = bg & 15;
  int n0 = nt * 64;
  int t = threadIdx.x, wid = t >> 6, l = t & 63;
  int llo = l & 15, lhi = l >> 4;

  if (t < 128) {
    *(u32*)(smem + 32768 + t * 4) = scpk[g * 128 + t];
    *(u32*)(smem + 33280 + t * 4) = shpk[g * 128 + t];
  }

  // ---- B-build: relu(bn1(Y1)) f16, 1 row per 8 threads ----
  {
    int rn = t >> 3, qq = t & 7;
    const u16* yrow = Y1 + ((size_t)bg * 4096 + n0 + rn) * 256;
    uint4 sreg[4];
    #pragma unroll
    for (int u = 0; u < 4; u++) sreg[u] = *(const uint4*)(yrow + (qq * 4 + u) * 8);
    __syncthreads();   // params visible
    const u32* scp = (const u32*)(smem + 32768);
    const u32* shp = (const u32*)(smem + 33280);
    #pragma unroll
    for (int u = 0; u < 4; u++) {
      int s = qq * 4 + u;
      const u32* yw = (const u32*)&sreg[u];
      uint4 o;
      u32* ow = (u32*)&o;
      #pragma unroll
      for (int w = 0; w < 4; w++) {
        int pairi = s * 4 + w;
        __half2 v = __hfma2(bits2h(yw[w]), bits2h(scp[pairi]), bits2h(shp[pairi]));
        ow[w] = pkmax0(h2bits(v));
      }
      *(uint4*)(smem + rn * 512 + ((s * 16) ^ ((rn & 15) << 4))) = o;
    }
  }
  __syncthreads();   // B ready

  f32x4 acc[2][4];
  #pragma unroll
  for (int i = 0; i < 2; i++)
    #pragma unroll
    for (int j = 0; j < 4; j++) acc[i][j] = (f32x4)0.f;

  for (int ks = 0; ks < 8; ks++) {
    f16x8 bfr[4], afr[2];
    #pragma unroll
    for (int i = 0; i < 2; i++)
      afr[i] = *(const f16x8*)(W2pk + (size_t)(((wid * 2 + i) * 8 + ks) * 64 + l) * 8);
    #pragma unroll
    for (int j = 0; j < 4; j++) {
      int rb = j * 16 + llo;
      bfr[j] = *(const f16x8*)(smem + rb * 512 + ((ks * 64 + lhi * 16) ^ ((rb & 15) << 4)));
    }
    #pragma unroll
    for (int i = 0; i < 2; i++)
      #pragma unroll
      for (int j = 0; j < 4; j++)
        acc[i][j] = __builtin_amdgcn_mfma_f32_16x16x32_f16(afr[i], bfr[j], acc[i][j], 0, 0, 0);
  }
  __syncthreads();   // all waves done reading B; smem reusable for out-tile

  // ---- epilogue: bias + stats + m-major out-LDS (256m x 128B) ----
  #pragma unroll
  for (int i = 0; i < 2; i++) {
    int mloc = wid * 32 + i * 16 + lhi * 4;
    float b0 = bias[mloc], b1 = bias[mloc + 1], b2 = bias[mloc + 2], b3 = bias[mloc + 3];
    float s0 = 0, s1 = 0, s2 = 0, s3 = 0, q0 = 0, q1 = 0, q2 = 0, q3 = 0;
    #pragma unroll
    for (int j = 0; j < 4; j++) {
      int n = j * 16 + llo;
      int slotn = (n >> 3) * 16, offn = (n * 2) & 15;
      float v0 = acc[i][j][0] + b0;
      float v1 = acc[i][j][1] + b1;
      float v2 = acc[i][j][2] + b2;
      float v3 = acc[i][j][3] + b3;
      s0 += v0; q0 += v0 * v0;
      s1 += v1; q1 += v1 * v1;
      s2 += v2; q2 += v2 * v2;
      s3 += v3; q3 += v3 * v3;
      *(u16*)(smem + (mloc + 0) * 128 + (slotn ^ (((mloc + 0) & 7) << 4)) + offn) =
          __half_as_ushort(__float2half_rn(v0));
      *(u16*)(smem + (mloc + 1) * 128 + (slotn ^ (((mloc + 1) & 7) << 4)) + offn) =
          __half_as_ushort(__float2half_rn(v1));
      *(u16*)(smem + (mloc + 2) * 128 + (slotn ^ (((mloc + 2) & 7) << 4)) + offn) =
          __half_as_ushort(__float2half_rn(v2));
      *(u16*)(smem + (mloc + 3) * 128 + (slotn ^ (((mloc + 3) & 7) << 4)) + offn) =
          __half_as_ushort(__float2half_rn(v3));
    }
    #pragma unroll
    for (int off = 1; off < 16; off <<= 1) {
      s0 += __shfl_xor(s0, off, 64); q0 += __shfl_xor(q0, off, 64);
      s1 += __shfl_xor(s1, off, 64); q1 += __shfl_xor(q1, off, 64);
      s2 += __shfl_xor(s2, off, 64); q2 += __shfl_xor(q2, off, 64);
      s3 += __shfl_xor(s3, off, 64); q3 += __shfl_xor(q3, off, 64);
    }
    if (llo == 0) {
      atomicAdd(&sumw[g * 256 + mloc], s0);     atomicAdd(&sqw[g * 256 + mloc], q0);
      atomicAdd(&sumw[g * 256 + mloc + 1], s1); atomicAdd(&sqw[g * 256 + mloc + 1], q1);
      atomicAdd(&sumw[g * 256 + mloc + 2], s2); atomicAdd(&sqw[g * 256 + mloc + 2], q2);
      atomicAdd(&sumw[g * 256 + mloc + 3], s3); atomicAdd(&sqw[g * 256 + mloc + 3], q3);
    }
  }
  __syncthreads();
  {
    int mr = t >> 1, hh = t & 1;
    u16* yrow = Y2 + ((size_t)b * 256 + mr) * (size_t)GN_ + (size_t)g * N_ + n0;
    #pragma unroll
    for (int u = 0; u < 4; u++) {
      int s = hh * 4 + u;
      uint4 v = *(const uint4*)(smem + mr * 128 + ((s * 16) ^ ((mr & 7) << 4)));
      *(uint4*)(yrow + s * 8) = v;
    }
  }
}

// ---------------- BN apply 2: Out = relu(bn2(Y2)), f16 -> f32 ----------------
__launch_bounds__(256)
__global__ void bnapply2_kernel(const u16* __restrict__ Y2, const float2* __restrict__ ss,
                                float* __restrict__ Out)
{
  int f8 = blockIdx.x * 256 + threadIdx.x;
  size_t base = (size_t)f8 * 8;
  int m = (int)((base >> 16) & 255);
  int g = (int)((base >> 12) & 15);
  float2 sc = ss[g * 256 + m];
  uint4 yv = *(const uint4*)(Y2 + base);
  const u32* yw = (const u32*)&yv;
  float4 a, b4;
  float* av = (float*)&a;
  float* bvv = (float*)&b4;
  #pragma unroll
  for (int i = 0; i < 2; i++) {
    float2 f = __half22float2(bits2h(yw[i]));
    av[2 * i]     = fmaxf(fmaf(f.x, sc.x, sc.y), 0.f);
    av[2 * i + 1] = fmaxf(fmaf(f.y, sc.x, sc.y), 0.f);
  }
  #pragma unroll
  for (int i = 0; i < 2; i++) {
    float2 f = __half22float2(bits2h(yw[2 + i]));
    bvv[2 * i]     = fmaxf(fmaf(f.x, sc.x, sc.y), 0.f);
    bvv[2 * i + 1] = fmaxf(fmaf(f.y, sc.x, sc.y), 0.f);
  }
  *(float4*)(Out + base) = a;
  *(float4*)(Out + base + 4) = b4;
}

// ---------------- launch ----------------
extern "C" void kernel_launch(void* const* d_in, const int* in_sizes, int n_in,
                              void* d_out, int out_size, void* d_ws, size_t ws_size,
                              hipStream_t stream)
{
  (void)in_sizes; (void)n_in; (void)out_size; (void)ws_size;
  const float* xyz1    = (const float*)d_in[0];
  const float* points1 = (const float*)d_in[1];
  const float* xyz2    = (const float*)d_in[3];
  const float* points2 = (const float*)d_in[4];
  const float* W1      = (const float*)d_in[6];
  const float* b1      = (const float*)d_in[7];
  const float* gamma1  = (const float*)d_in[8];
  const float* beta1   = (const float*)d_in[9];
  const float* W2      = (const float*)d_in[10];
  const float* b2      = (const float*)d_in[11];
  const float* gamma2  = (const float*)d_in[12];
  const float* beta2   = (const float*)d_in[13];
  float* out = (float*)d_out;
  char* ws = (char*)d_ws;

  u16*    W1pk  = (u16*)(ws + OFF_W1PK);
  u16*    W2pk  = (u16*)(ws + OFF_W2PK);
  float4* xyz2p = (float4*)(ws + OFF_XYZ2P);
  float*  sum1  = (float*)(ws + OFF_SUM1);
  float*  sq1   = (float*)(ws + OFF_SQ1);
  float*  sum2  = (float*)(ws + OFF_SUM2);
  float*  sq2   = (float*)(ws + OFF_SQ2);
  u32*    scpk1 = (u32*)(ws + OFF_SCPK1);
  u32*    shpk1 = (u32*)(ws + OFF_SHPK1);
  float2* ss2   = (float2*)(ws + OFF_SS2);
  u16*    p2T   = (u16*)(ws + OFF_P2T);
  u16*    Y2    = (u16*)(ws + OFF_Y2);
  u16*    Y1    = (u16*)(ws + OFF_Y1);

  prep_kernel<<<176, 256, 0, stream>>>(W1, W2, xyz2, W1pk, W2pk, xyz2p, sum1);
  t2_kernel<<<2048, 256, 0, stream>>>(points2, p2T);
  gemm1_kernel<<<2048, 512, 0, stream>>>(W1pk, points1, p2T, xyz1, xyz2p, b1, sum1, sq1, Y1);
  bnfin_kernel<<<16, 256, 0, stream>>>(sum1, sq1, gamma1, beta1, nullptr, scpk1, shpk1);
  gemm2_kernel<<<2048, 512, 0, stream>>>(W2pk, Y1, scpk1, shpk1, b2, sum2, sq2, Y2);
  bnfin_kernel<<<16, 256, 0, stream>>>(sum2, sq2, gamma2, beta2, ss2, nullptr, nullptr);
  bnapply2_kernel<<<16384, 256, 0, stream>>>(Y2, ss2, out);
}

// Round 19
// 222.728 us; speedup vs baseline: 1.1129x; 1.0104x over previous
//
#include <hip/hip_runtime.h>
#include <hip/hip_bf16.h>
#include <hip/hip_fp16.h>

// Problem constants
#define B_    2
#define G_    16
#define N_    4096
#define S_    1024
#define D1_   128
#define D2_   256
#define CIN_  384
#define BG_   32
#define GN_   65536
#define GS_   16384

typedef unsigned int u32;
typedef unsigned short u16;
typedef _Float16 f16x8 __attribute__((ext_vector_type(8)));
typedef float f32x4 __attribute__((ext_vector_type(4)));

__device__ __forceinline__ u32 h2bits(__half2 h) { union { __half2 h; u32 u; } c; c.h = h; return c.u; }
__device__ __forceinline__ __half2 bits2h(u32 u) { union { __half2 h; u32 u; } c; c.u = u; return c.h; }
__device__ __forceinline__ u32 pkmax0(u32 v) {
  u32 r; asm("v_pk_max_f16 %0, %1, %2" : "=v"(r) : "v"(v), "v"(0)); return r;
}

// ---------------- workspace layout (bytes) ----------------
#define OFF_W1PK   0u           // 256*384*2 fragment-packed
#define OFF_W2PK   196608u      // 256*256*2 fragment-packed
#define OFF_XYZ2P  327680u      // 32*256*4*16
#define OFF_SUM1   851968u      // 4 x 16KB contiguous (sum1,sq1,sum2,sq2)
#define OFF_SQ1    868352u
#define OFF_SUM2   884736u
#define OFF_SQ2    901120u
#define OFF_SCPK1  917504u      // 16*128*4 packed half2 scale (BN1)
#define OFF_SHPK1  925696u      // packed half2 shift (BN1)
#define OFF_SS2    950272u      // float2 (BN2)
#define OFF_P2T    5177344u     // 32*1024*256*2 f16
#define OFF_Y2     21954560u    // f16 pre-BN2, OUT layout [b][m][gn]
#define OFF_Y1     122617856u   // f16 pre-BN1, [bg*4096+n][256]

// ---------------- prep: pack weights into MFMA-fragment order, zero stats, pack xyz2 ----------------
__launch_bounds__(256)
__global__ void prep_kernel(const float* __restrict__ W1, const float* __restrict__ W2,
                            const float* __restrict__ xyz2,
                            u16* __restrict__ W1pk, u16* __restrict__ W2pk,
                            float4* __restrict__ xyz2p, float* __restrict__ zeros)
{
  int idx = blockIdx.x * 256 + threadIdx.x;
  if (idx < 12288) {          // W1 fragments
    int lane = idx & 63, ks = (idx >> 6) % 12, mr = idx / (64 * 12);
    int m = mr * 16 + (lane & 15), k = ks * 32 + (lane >> 4) * 8;
    const float* src = W1 + (size_t)m * 384 + k;
    u16* dst = W1pk + (size_t)idx * 8;
    #pragma unroll
    for (int e = 0; e < 8; e++) dst[e] = __half_as_ushort(__float2half_rn(src[e]));
    return;
  }
  idx -= 12288;
  if (idx < 8192) {           // W2 fragments
    int lane = idx & 63, ks = (idx >> 6) % 8, mr = idx / (64 * 8);
    int m = mr * 16 + (lane & 15), k = ks * 32 + (lane >> 4) * 8;
    const float* src = W2 + (size_t)m * 256 + k;
    u16* dst = W2pk + (size_t)idx * 8;
    #pragma unroll
    for (int e = 0; e < 8; e++) dst[e] = __half_as_ushort(__float2half_rn(src[e]));
    return;
  }
  idx -= 8192;
  if (idx < 16384) { zeros[idx] = 0.f; return; }
  idx -= 16384;
  int bg = idx >> 8, q = idx & 255;
  int b = bg >> 4, g = bg & 15;
  const float* base = xyz2 + (size_t)b * 3 * GS_ + (size_t)g * S_ + q * 4;
  float4 X = *(const float4*)(base);
  float4 Y = *(const float4*)(base + GS_);
  float4 Z = *(const float4*)(base + 2 * GS_);
  float4 M;
  M.x = X.x*X.x + Y.x*Y.x + Z.x*Z.x;
  M.y = X.y*X.y + Y.y*Y.y + Z.y*Z.y;
  M.z = X.z*X.z + Y.z*Y.z + Z.z*Z.z;
  M.w = X.w*X.w + Y.w*Y.w + Z.w*Z.w;
  float4* dst = xyz2p + (size_t)idx * 4;
  dst[0] = X; dst[1] = Y; dst[2] = Z; dst[3] = M;
}

// ---------------- transpose points2 -> p2T [s][256] f16 ----------------
__launch_bounds__(256)
__global__ void t2_kernel(const float* __restrict__ p2, u16* __restrict__ p2T)
{
  __shared__ float tl[64][65];
  int bx = blockIdx.x;
  int bg = bx >> 6, r = bx & 63;
  int ct = r >> 4, st = r & 15;
  int c0 = ct * 64, s0 = st * 64;
  int b = bg >> 4, g = bg & 15;
  int t = threadIdx.x, lane = t & 63, w = t >> 6;
  const float* src = p2 + (size_t)b * D2_ * GS_ + (size_t)g * S_ + s0 + lane;
  #pragma unroll
  for (int i = 0; i < 16; i++) {
    int row = w * 16 + i;
    tl[row][lane] = src[(size_t)(c0 + row) * GS_];
  }
  __syncthreads();
  int cp = t & 31, sr = t >> 5;
  #pragma unroll
  for (int i = 0; i < 8; i++) {
    int sl = sr * 8 + i;
    u32 v = h2bits(__floats2half2_rn(tl[2 * cp][sl], tl[2 * cp + 1][sl]));
    *(u32*)(p2T + (((size_t)bg * 1024 + s0 + sl) * 256 + c0 + 2 * cp)) = v;
  }
}

// ================= GEMM1 (fused kNN, wave-uniform + scalar loads): 512 thr =========
// Phase 0: kNN for this block's 64 queries. lane(t&63)=query, wave(t>>6)=source-eighth;
// q forced to SGPR via readfirstlane -> s_load path (R18, verified +7%).
// Distance slots updated via min/med3 (value-identical to cascade; 2 fewer VALU/cand);
// index cndmasks keep the identical pre-update compares -> bit-identical selection.
// Merge 8 partials via LDS in ascending-eighth order (strict <, R8 tie semantics).
// Then R11 structure: B 64x768B XOR((r&15)<<4) (49152), barrier-free K-loop, out-tile reuses B.
__launch_bounds__(512, 6)
__global__ void gemm1_kernel(const u16* __restrict__ W1pk, const float* __restrict__ points1,
                             const u16* __restrict__ p2T, const float* __restrict__ xyz1,
                             const float4* __restrict__ xyz2p,
                             const float* __restrict__ bias,
                             float* __restrict__ sumw, float* __restrict__ sqw,
                             u16* __restrict__ Y1)
{
  __shared__ __align__(16) char smem[49152];
  int bx = blockIdx.x;
  int bg = bx >> 6, nt = bx & 63;
  int b = bg >> 4, g = bg & 15;
  int n0 = nt * 64;
  int t = threadIdx.x, wid = t >> 6, l = t & 63;
  int llo = l & 15, lhi = l >> 4;

  // ---- fused kNN: query = l, source-eighth = wid (wave-uniform xp addressing) ----
  {
    const float* x1b = xyz1 + (size_t)b * 3 * GN_ + (size_t)g * N_ + n0 + l;
    float x = x1b[0], y = x1b[GN_], z = x1b[2 * GN_];
    const float4* xp = xyz2p + (size_t)bg * 1024;
    float d0 = 3.4e38f, d1 = 3.4e38f, d2 = 3.4e38f;
    int i0 = 0, i1 = 0, i2 = 0;
    for (int k = 0; k < 32; k++) {
      // wave-uniform quad index, FORCED to SGPR -> scalar loads below
      int q = __builtin_amdgcn_readfirstlane(wid * 32 + k);
      float4 X = xp[q * 4 + 0], Y = xp[q * 4 + 1], Z = xp[q * 4 + 2], M = xp[q * 4 + 3];
      const float* Xa = (const float*)&X;
      const float* Ya = (const float*)&Y;
      const float* Za = (const float*)&Z;
      const float* Ma = (const float*)&M;
      #pragma unroll
      for (int u = 0; u < 4; u++) {
        float cr = x * Xa[u];
        cr = fmaf(y, Ya[u], cr);
        cr = fmaf(z, Za[u], cr);
        float d = fmaf(-2.f, cr, Ma[u]); // biased by -|x1|^2; consistent within a query
        int s = q * 4 + u;
        bool cc2 = d < d2, cc1 = d < d1, cc0 = d < d0;
        i2 = cc1 ? i1 : (cc2 ? s : i2);
        i1 = cc0 ? i0 : (cc1 ? s : i1);
        i0 = cc0 ? s : i0;
        d2 = __builtin_amdgcn_fmed3f(d1, d2, d);   // == cc1 ? d1 : (cc2 ? d : d2)
        d1 = __builtin_amdgcn_fmed3f(d0, d1, d);   // == cc0 ? d0 : (cc1 ? d : d1)
        d0 = fminf(d0, d);
      }
    }
    float* sd = (float*)smem;            // [3][512] = 6144 B
    int*   si = (int*)(smem + 6144);     // [3][512] = 6144 B
    sd[0 * 512 + t] = d0; sd[1 * 512 + t] = d1; sd[2 * 512 + t] = d2;
    si[0 * 512 + t] = i0; si[1 * 512 + t] = i1; si[2 * 512 + t] = i2;
    __syncthreads();
    if (t < 64) {                        // wid==0 thread merges eighths 1..7 for query t
      float D0 = d0, D1 = d1, D2 = d2;
      int I0 = i0, I1 = i1, I2 = i2;
      #pragma unroll
      for (int e = 1; e < 8; e++) {
        int idx = e * 64 + t;
        #pragma unroll
        for (int c = 0; c < 3; c++) {
          float d = sd[c * 512 + idx];
          int s = si[c * 512 + idx];
          bool cc0 = d < D0, cc1 = d < D1, cc2 = d < D2;
          I2 = cc1 ? I1 : (cc2 ? s : I2);
          I1 = cc0 ? I0 : (cc1 ? s : I1);
          I0 = cc0 ? s : I0;
          D2 = __builtin_amdgcn_fmed3f(D1, D2, d);
          D1 = __builtin_amdgcn_fmed3f(D0, D1, d);
          D0 = fminf(D0, d);
        }
      }
      float m1 = x * x + y * y + z * z;
      float t0 = fmaxf(D0 + m1, 0.f), t1 = fmaxf(D1 + m1, 0.f), t2v = fmaxf(D2 + m1, 0.f);
      float w0 = 1.f / (t0 + 1e-8f);
      float w1 = 1.f / (t1 + 1e-8f);
      float w2 = 1.f / (t2v + 1e-8f);
      float inv = 1.f / (w0 + w1 + w2);
      uint4 rec;
      rec.x = h2bits(__floats2half2_rn(w0 * inv, w1 * inv));
      rec.y = (u32)__half_as_ushort(__float2half_rn(w2 * inv));
      rec.z = (u32)I0 | ((u32)I1 << 16);
      rec.w = (u32)I2;
      *(uint4*)(smem + 12288 + t * 16) = rec;
    }
    __syncthreads();
  }
  uint4 kp = *(const uint4*)(smem + 12288 + (t >> 3) * 16);  // rec for B-build row t>>3
  __syncthreads();   // all kp in regs; smem free for B-tile

  int qr = t >> 3, c8 = t & 7;            // B-build row, channel-eighth

  // ---- B-build: interp ch 128..383, 1 row per 8 threads, 4 chunks each ----
  {
    const u16* p2b = p2T + (size_t)bg * 1024 * 256;
    __half2 w0 = __half2half2(__low2half(bits2h(kp.x)));
    __half2 w1 = __half2half2(__high2half(bits2h(kp.x)));
    __half2 w2 = __half2half2(__low2half(bits2h(kp.y)));
    int i0 = kp.z & 0xffff, i1 = kp.z >> 16, i2 = kp.w & 0xffff;
    const u16* r0 = p2b + (size_t)i0 * 256;
    const u16* r1 = p2b + (size_t)i1 * 256;
    const u16* r2 = p2b + (size_t)i2 * 256;
    #pragma unroll
    for (int u = 0; u < 4; u++) {
      int ch = c8 + 8 * u;
      uint4 q0 = *(const uint4*)(r0 + ch * 8);
      uint4 q1 = *(const uint4*)(r1 + ch * 8);
      uint4 q2 = *(const uint4*)(r2 + ch * 8);
      const u32* a0 = (const u32*)&q0;
      const u32* a1 = (const u32*)&q1;
      const u32* a2 = (const u32*)&q2;
      uint4 o;
      u32* ow = (u32*)&o;
      #pragma unroll
      for (int w = 0; w < 4; w++) {
        __half2 v = __hmul2(w2, bits2h(a2[w]));
        v = __hfma2(w1, bits2h(a1[w]), v);
        v = __hfma2(w0, bits2h(a0[w]), v);
        ow[w] = h2bits(v);
      }
      *(uint4*)(smem + qr * 768 + ((256 + ch * 16) ^ ((qr & 15) << 4))) = o;
    }
    // p1 ch 0..127 transpose: thread owns row (t&63), 16 channels
    int row = t & 63, chgrp = t >> 6;
    const float* p1c = points1 + ((size_t)b * 128 + chgrp * 16) * (size_t)GN_
                     + (size_t)g * N_ + n0 + row;
    #pragma unroll
    for (int cp = 0; cp < 8; cp++) {
      int c = chgrp * 16 + cp * 2;
      u32 pk = h2bits(__floats2half2_rn(p1c[(size_t)(cp * 2) * GN_],
                                        p1c[(size_t)(cp * 2 + 1) * GN_]));
      *(u32*)(smem + row * 768 + ((c * 2) ^ ((row & 15) << 4))) = pk;
    }
  }
  __syncthreads();   // B ready

  f32x4 acc[2][4];
  #pragma unroll
  for (int i = 0; i < 2; i++)
    #pragma unroll
    for (int j = 0; j < 4; j++) acc[i][j] = (f32x4)0.f;

  // ---- K-loop: barrier-free. afr from global (L2), bfr from LDS ----
  for (int ks = 0; ks < 12; ks++) {
    f16x8 bfr[4], afr[2];
    #pragma unroll
    for (int i = 0; i < 2; i++)
      afr[i] = *(const f16x8*)(W1pk + (size_t)(((wid * 2 + i) * 12 + ks) * 64 + l) * 8);
    #pragma unroll
    for (int j = 0; j < 4; j++) {
      int rb = j * 16 + llo;
      bfr[j] = *(const f16x8*)(smem + rb * 768 + ((ks * 64 + lhi * 16) ^ ((rb & 15) << 4)));
    }
    #pragma unroll
    for (int i = 0; i < 2; i++)
      #pragma unroll
      for (int j = 0; j < 4; j++)
        acc[i][j] = __builtin_amdgcn_mfma_f32_16x16x32_f16(afr[i], bfr[j], acc[i][j], 0, 0, 0);
  }
  __syncthreads();   // all waves done reading B; smem reusable for out-tile

  // ---- epilogue: bias + stats + n-major out-LDS (64 n x 512B) ----
  #pragma unroll
  for (int i = 0; i < 2; i++) {
    int mloc = wid * 32 + i * 16 + lhi * 4;
    float b0 = bias[mloc], b1 = bias[mloc + 1], b2 = bias[mloc + 2], b3 = bias[mloc + 3];
    float s0 = 0, s1 = 0, s2 = 0, s3 = 0, q0 = 0, q1 = 0, q2 = 0, q3 = 0;
    int slotb = (mloc * 2) & ~15, off8 = (mloc * 2) & 15;
    #pragma unroll
    for (int j = 0; j < 4; j++) {
      int n = j * 16 + llo;
      float v0 = acc[i][j][0] + b0;
      float v1 = acc[i][j][1] + b1;
      float v2 = acc[i][j][2] + b2;
      float v3 = acc[i][j][3] + b3;
      s0 += v0; q0 += v0 * v0;
      s1 += v1; q1 += v1 * v1;
      s2 += v2; q2 += v2 * v2;
      s3 += v3; q3 += v3 * v3;
      int base = n * 512 + (slotb ^ ((n & 7) << 4)) + off8;
      *(u32*)(smem + base) = h2bits(__floats2half2_rn(v0, v1));
      *(u32*)(smem + base + 4) = h2bits(__floats2half2_rn(v2, v3));
    }
    #pragma unroll
    for (int off = 1; off < 16; off <<= 1) {
      s0 += __shfl_xor(s0, off, 64); q0 += __shfl_xor(q0, off, 64);
      s1 += __shfl_xor(s1, off, 64); q1 += __shfl_xor(q1, off, 64);
      s2 += __shfl_xor(s2, off, 64); q2 += __shfl_xor(q2, off, 64);
      s3 += __shfl_xor(s3, off, 64); q3 += __shfl_xor(q3, off, 64);
    }
    if (llo == 0) {
      atomicAdd(&sumw[g * 256 + mloc], s0);     atomicAdd(&sqw[g * 256 + mloc], q0);
      atomicAdd(&sumw[g * 256 + mloc + 1], s1); atomicAdd(&sqw[g * 256 + mloc + 1], q1);
      atomicAdd(&sumw[g * 256 + mloc + 2], s2); atomicAdd(&sqw[g * 256 + mloc + 2], q2);
      atomicAdd(&sumw[g * 256 + mloc + 3], s3); atomicAdd(&sqw[g * 256 + mloc + 3], q3);
    }
  }
  __syncthreads();
  {
    int rn = t >> 3, cq = t & 7;
    u16* yrow = Y1 + ((size_t)bg * 4096 + n0 + rn) * 256;
    #pragma unroll
    for (int u = 0; u < 4; u++) {
      int s = u * 8 + cq;
      uint4 v = *(const uint4*)(smem + rn * 512 + ((s * 16) ^ ((rn & 7) << 4)));
      *(uint4*)(yrow + s * 8) = v;
    }
  }
}

// ---------------- BN finalize ----------------
__global__ void bnfin_kernel(const float* __restrict__ sum, const float* __restrict__ sq,
                             const float* __restrict__ gamma, const float* __restrict__ beta,
                             float2* __restrict__ ss, u32* __restrict__ scpk, u32* __restrict__ shpk)
{
  __shared__ float scl[256], shl[256];
  int g = blockIdx.x, m = threadIdx.x;
  int i = g * 256 + m;
  float mean = sum[i] * (1.f / 8192.f);
  float var = sq[i] * (1.f / 8192.f) - mean * mean;
  var = fmaxf(var, 0.f);
  float rstd = rsqrtf(var + 1e-5f);
  float sc = gamma[m] * rstd;
  float sh = beta[m] - mean * sc;
  if (ss) ss[i] = make_float2(sc, sh);
  if (scpk) {
    scl[m] = sc; shl[m] = sh;
    __syncthreads();
    if (m < 128) {
      scpk[g * 128 + m] = h2bits(__floats2half2_rn(scl[2 * m], scl[2 * m + 1]));
      shpk[g * 128 + m] = h2bits(__floats2half2_rn(shl[2 * m], shl[2 * m + 1]));
    }
  }
}

// ================= GEMM2: 512 thr (8 waves x 32m), M=256 x N=64, K=256 (R11) =================
__launch_bounds__(512, 6)
__global__ void gemm2_kernel(const u16* __restrict__ W2pk, const u16* __restrict__ Y1,
                             const u32* __restrict__ scpk, const u32* __restrict__ shpk,
                             const float* __restrict__ bias,
                             float* __restrict__ sumw, float* __restrict__ sqw,
                             u16* __restrict__ Y2)
{
  __shared__ __align__(16) char smem[33792];
  int bx = blockIdx.x;
  int bg = bx >> 6, nt = bx & 63;
  int b = bg >> 4, g = bg & 15;
  int n0 = nt * 64;
  int t = threadIdx.x, wid = t >> 6, l = t & 63;
  int llo = l & 15, lhi = l >> 4;

  if (t < 128) {
    *(u32*)(smem + 32768 + t * 4) = scpk[g * 128 + t];
    *(u32*)(smem + 33280 + t * 4) = shpk[g * 128 + t];
  }

  // ---- B-build: relu(bn1(Y1)) f16, 1 row per 8 threads ----
  {
    int rn = t >> 3, qq = t & 7;
    const u16* yrow = Y1 + ((size_t)bg * 4096 + n0 + rn) * 256;
    uint4 sreg[4];
    #pragma unroll
    for (int u = 0; u < 4; u++) sreg[u] = *(const uint4*)(yrow + (qq * 4 + u) * 8);
    __syncthreads();   // params visible
    const u32* scp = (const u32*)(smem + 32768);
    const u32* shp = (const u32*)(smem + 33280);
    #pragma unroll
    for (int u = 0; u < 4; u++) {
      int s = qq * 4 + u;
      const u32* yw = (const u32*)&sreg[u];
      uint4 o;
      u32* ow = (u32*)&o;
      #pragma unroll
      for (int w = 0; w < 4; w++) {
        int pairi = s * 4 + w;
        __half2 v = __hfma2(bits2h(yw[w]), bits2h(scp[pairi]), bits2h(shp[pairi]));
        ow[w] = pkmax0(h2bits(v));
      }
      *(uint4*)(smem + rn * 512 + ((s * 16) ^ ((rn & 15) << 4))) = o;
    }
  }
  __syncthreads();   // B ready

  f32x4 acc[2][4];
  #pragma unroll
  for (int i = 0; i < 2; i++)
    #pragma unroll
    for (int j = 0; j < 4; j++) acc[i][j] = (f32x4)0.f;

  for (int ks = 0; ks < 8; ks++) {
    f16x8 bfr[4], afr[2];
    #pragma unroll
    for (int i = 0; i < 2; i++)
      afr[i] = *(const f16x8*)(W2pk + (size_t)(((wid * 2 + i) * 8 + ks) * 64 + l) * 8);
    #pragma unroll
    for (int j = 0; j < 4; j++) {
      int rb = j * 16 + llo;
      bfr[j] = *(const f16x8*)(smem + rb * 512 + ((ks * 64 + lhi * 16) ^ ((rb & 15) << 4)));
    }
    #pragma unroll
    for (int i = 0; i < 2; i++)
      #pragma unroll
      for (int j = 0; j < 4; j++)
        acc[i][j] = __builtin_amdgcn_mfma_f32_16x16x32_f16(afr[i], bfr[j], acc[i][j], 0, 0, 0);
  }
  __syncthreads();   // all waves done reading B; smem reusable for out-tile

  // ---- epilogue: bias + stats + m-major out-LDS (256m x 128B) ----
  #pragma unroll
  for (int i = 0; i < 2; i++) {
    int mloc = wid * 32 + i * 16 + lhi * 4;
    float b0 = bias[mloc], b1 = bias[mloc + 1], b2 = bias[mloc + 2], b3 = bias[mloc + 3];
    float s0 = 0, s1 = 0, s2 = 0, s3 = 0, q0 = 0, q1 = 0, q2 = 0, q3 = 0;
    #pragma unroll
    for (int j = 0; j < 4; j++) {
      int n = j * 16 + llo;
      int slotn = (n >> 3) * 16, offn = (n * 2) & 15;
      float v0 = acc[i][j][0] + b0;
      float v1 = acc[i][j][1] + b1;
      float v2 = acc[i][j][2] + b2;
      float v3 = acc[i][j][3] + b3;
      s0 += v0; q0 += v0 * v0;
      s1 += v1; q1 += v1 * v1;
      s2 += v2; q2 += v2 * v2;
      s3 += v3; q3 += v3 * v3;
      *(u16*)(smem + (mloc + 0) * 128 + (slotn ^ (((mloc + 0) & 7) << 4)) + offn) =
          __half_as_ushort(__float2half_rn(v0));
      *(u16*)(smem + (mloc + 1) * 128 + (slotn ^ (((mloc + 1) & 7) << 4)) + offn) =
          __half_as_ushort(__float2half_rn(v1));
      *(u16*)(smem + (mloc + 2) * 128 + (slotn ^ (((mloc + 2) & 7) << 4)) + offn) =
          __half_as_ushort(__float2half_rn(v2));
      *(u16*)(smem + (mloc + 3) * 128 + (slotn ^ (((mloc + 3) & 7) << 4)) + offn) =
          __half_as_ushort(__float2half_rn(v3));
    }
    #pragma unroll
    for (int off = 1; off < 16; off <<= 1) {
      s0 += __shfl_xor(s0, off, 64); q0 += __shfl_xor(q0, off, 64);
      s1 += __shfl_xor(s1, off, 64); q1 += __shfl_xor(q1, off, 64);
      s2 += __shfl_xor(s2, off, 64); q2 += __shfl_xor(q2, off, 64);
      s3 += __shfl_xor(s3, off, 64); q3 += __shfl_xor(q3, off, 64);
    }
    if (llo == 0) {
      atomicAdd(&sumw[g * 256 + mloc], s0);     atomicAdd(&sqw[g * 256 + mloc], q0);
      atomicAdd(&sumw[g * 256 + mloc + 1], s1); atomicAdd(&sqw[g * 256 + mloc + 1], q1);
      atomicAdd(&sumw[g * 256 + mloc + 2], s2); atomicAdd(&sqw[g * 256 + mloc + 2], q2);
      atomicAdd(&sumw[g * 256 + mloc + 3], s3); atomicAdd(&sqw[g * 256 + mloc + 3], q3);
    }
  }
  __syncthreads();
  {
    int mr = t >> 1, hh = t & 1;
    u16* yrow = Y2 + ((size_t)b * 256 + mr) * (size_t)GN_ + (size_t)g * N_ + n0;
    #pragma unroll
    for (int u = 0; u < 4; u++) {
      int s = hh * 4 + u;
      uint4 v = *(const uint4*)(smem + mr * 128 + ((s * 16) ^ ((mr & 7) << 4)));
      *(uint4*)(yrow + s * 8) = v;
    }
  }
}

// ---------------- BN apply 2: Out = relu(bn2(Y2)), f16 -> f32 ----------------
__launch_bounds__(256)
__global__ void bnapply2_kernel(const u16* __restrict__ Y2, const float2* __restrict__ ss,
                                float* __restrict__ Out)
{
  int f8 = blockIdx.x * 256 + threadIdx.x;
  size_t base = (size_t)f8 * 8;
  int m = (int)((base >> 16) & 255);
  int g = (int)((base >> 12) & 15);
  float2 sc = ss[g * 256 + m];
  uint4 yv = *(const uint4*)(Y2 + base);
  const u32* yw = (const u32*)&yv;
  float4 a, b4;
  float* av = (float*)&a;
  float* bvv = (float*)&b4;
  #pragma unroll
  for (int i = 0; i < 2; i++) {
    float2 f = __half22float2(bits2h(yw[i]));
    av[2 * i]     = fmaxf(fmaf(f.x, sc.x, sc.y), 0.f);
    av[2 * i + 1] = fmaxf(fmaf(f.y, sc.x, sc.y), 0.f);
  }
  #pragma unroll
  for (int i = 0; i < 2; i++) {
    float2 f = __half22float2(bits2h(yw[2 + i]));
    bvv[2 * i]     = fmaxf(fmaf(f.x, sc.x, sc.y), 0.f);
    bvv[2 * i + 1] = fmaxf(fmaf(f.y, sc.x, sc.y), 0.f);
  }
  *(float4*)(Out + base) = a;
  *(float4*)(Out + base + 4) = b4;
}

// ---------------- launch ----------------
extern "C" void kernel_launch(void* const* d_in, const int* in_sizes, int n_in,
                              void* d_out, int out_size, void* d_ws, size_t ws_size,
                              hipStream_t stream)
{
  (void)in_sizes; (void)n_in; (void)out_size; (void)ws_size;
  const float* xyz1    = (const float*)d_in[0];
  const float* points1 = (const float*)d_in[1];
  const float* xyz2    = (const float*)d_in[3];
  const float* points2 = (const float*)d_in[4];
  const float* W1      = (const float*)d_in[6];
  const float* b1      = (const float*)d_in[7];
  const float* gamma1  = (const float*)d_in[8];
  const float* beta1   = (const float*)d_in[9];
  const float* W2      = (const float*)d_in[10];
  const float* b2      = (const float*)d_in[11];
  const float* gamma2  = (const float*)d_in[12];
  const float* beta2   = (const float*)d_in[13];
  float* out = (float*)d_out;
  char* ws = (char*)d_ws;

  u16*    W1pk  = (u16*)(ws + OFF_W1PK);
  u16*    W2pk  = (u16*)(ws + OFF_W2PK);
  float4* xyz2p = (float4*)(ws + OFF_XYZ2P);
  float*  sum1  = (float*)(ws + OFF_SUM1);
  float*  sq1   = (float*)(ws + OFF_SQ1);
  float*  sum2  = (float*)(ws + OFF_SUM2);
  float*  sq2   = (float*)(ws + OFF_SQ2);
  u32*    scpk1 = (u32*)(ws + OFF_SCPK1);
  u32*    shpk1 = (u32*)(ws + OFF_SHPK1);
  float2* ss2   = (float2*)(ws + OFF_SS2);
  u16*    p2T   = (u16*)(ws + OFF_P2T);
  u16*    Y2    = (u16*)(ws + OFF_Y2);
  u16*    Y1    = (u16*)(ws + OFF_Y1);

  prep_kernel<<<176, 256, 0, stream>>>(W1, W2, xyz2, W1pk, W2pk, xyz2p, sum1);
  t2_kernel<<<2048, 256, 0, stream>>>(points2, p2T);
  gemm1_kernel<<<2048, 512, 0, stream>>>(W1pk, points1, p2T, xyz1, xyz2p, b1, sum1, sq1, Y1);
  bnfin_kernel<<<16, 256, 0, stream>>>(sum1, sq1, gamma1, beta1, nullptr, scpk1, shpk1);
  gemm2_kernel<<<2048, 512, 0, stream>>>(W2pk, Y1, scpk1, shpk1, b2, sum2, sq2, Y2);
  bnfin_kernel<<<16, 256, 0, stream>>>(sum2, sq2, gamma2, beta2, ss2, nullptr, nullptr);
  bnapply2_kernel<<<16384, 256, 0, stream>>>(Y2, ss2, out);
}